// Round 7
// baseline (485.574 us; speedup 1.0000x reference)
//
#include <hip/hip_runtime.h>

#define DHID 128
#define BCAP 10240         // per-bucket capacity (mean 8163, 23 sigma)
#define PCHUNK 4096        // edges per partition block
#define XS_LD 136          // LDS row stride in fp16 elems (128 + 8 pad -> even banks)

typedef _Float16 h2 __attribute__((ext_vector_type(2)));
typedef _Float16 h4 __attribute__((ext_vector_type(4)));
typedef _Float16 h8 __attribute__((ext_vector_type(8)));
typedef _Float16 f16x8 __attribute__((ext_vector_type(8)));
typedef float    f32x4 __attribute__((ext_vector_type(4)));

// ---------------- phase 1: partition edges into 512-node buckets ----------------
// packed entry: (dst & 511) << 17 | src   (src < 2^17)
__global__ __launch_bounds__(256) void k_partition(const int* __restrict__ ei, int E, int nbuck,
                                                   int* __restrict__ bucket_cursor,
                                                   unsigned* __restrict__ packed) {
    __shared__ unsigned sdata[PCHUNK];
    __shared__ int lcnt[256], lbase[256], loff[256], lcur[256], sscan[256];
    int t = threadIdx.x;
    int e0 = blockIdx.x * PCHUNK;
    lcnt[t] = 0;
    __syncthreads();

    for (int i = t; i < PCHUNK; i += 256) {
        int e = e0 + i;
        if (e < E) {
            int d = ei[E + e];
            atomicAdd(&lcnt[d >> 9], 1);
        }
    }
    __syncthreads();

    int c = lcnt[t];
    sscan[t] = c;
    __syncthreads();
    for (int off = 1; off < 256; off <<= 1) {
        int v = (t >= off) ? sscan[t - off] : 0;
        __syncthreads();
        sscan[t] += v;
        __syncthreads();
    }
    loff[t] = sscan[t] - c;
    if (t < nbuck && c > 0) lbase[t] = atomicAdd(&bucket_cursor[t], c);
    lcur[t] = sscan[t] - c;
    __syncthreads();

    for (int i = t; i < PCHUNK; i += 256) {
        int e = e0 + i;
        if (e < E) {
            int s = ei[e];
            int d = ei[E + e];
            int b = d >> 9;
            int pos = atomicAdd(&lcur[b], 1);
            sdata[pos] = ((unsigned)(d & 511) << 17) | (unsigned)s;
        }
    }
    __syncthreads();

    int wid = t >> 6, lane = t & 63;
    for (int b = wid; b < nbuck; b += 4) {
        int cb = lcnt[b];
        if (cb == 0) continue;
        int gbase = b * BCAP + lbase[b];
        int sbase = loff[b];
        for (int k = lane; k < cb; k += 64) packed[gbase + k] = sdata[sbase + k];
    }
}

// ---------------- phase 2a: per-node degree ----------------
__global__ __launch_bounds__(256) void k_p2a(const unsigned* __restrict__ packed,
                                             const int* __restrict__ bucket_cursor,
                                             int* __restrict__ cnt, int N) {
    __shared__ int c512[512];
    int t = threadIdx.x, b = blockIdx.x;
    c512[t] = 0; c512[t + 256] = 0;
    __syncthreads();
    int m = bucket_cursor[b];
    const unsigned* pb = packed + (size_t)b * BCAP;
    for (int i = t; i < m; i += 256) atomicAdd(&c512[pb[i] >> 17], 1);
    __syncthreads();
    int base = b << 9;
#pragma unroll
    for (int j = 0; j < 2; ++j) {
        int node = base + t + j * 256;
        if (node < N) cnt[node] = c512[t + j * 256];
    }
}

__global__ void k_dinv(const int* __restrict__ cnt, float* __restrict__ dinv, int N) {
    int i = blockIdx.x * 256 + threadIdx.x;
    if (i < N) dinv[i] = rsqrtf((float)(cnt[i] + 1));
}

__global__ void k_reduce(const int* __restrict__ cnt, int* __restrict__ partial, int N) {
    __shared__ int s[256];
    int t = threadIdx.x;
    int i = blockIdx.x * 256 + t;
    s[t] = (i < N) ? cnt[i] : 0;
    __syncthreads();
    for (int st = 128; st > 0; st >>= 1) {
        if (t < st) s[t] += s[t + st];
        __syncthreads();
    }
    if (t == 0) partial[blockIdx.x] = s[0];
}

__global__ void k_scan_partials(const int* __restrict__ partial, int* __restrict__ blockoff, int NB) {
    __shared__ int s[1024];
    int t = threadIdx.x;
    s[t] = (t < NB) ? partial[t] : 0;
    __syncthreads();
    for (int off = 1; off < 1024; off <<= 1) {
        int v = (t >= off) ? s[t - off] : 0;
        __syncthreads();
        s[t] += v;
        __syncthreads();
    }
    if (t < NB) blockoff[t] = (t == 0) ? 0 : s[t - 1];
}

__global__ void k_scan_block(const int* __restrict__ cnt, const int* __restrict__ blockoff,
                             int* __restrict__ row_ptr, int N, int E) {
    __shared__ int s[256];
    int t = threadIdx.x;
    int i = blockIdx.x * 256 + t;
    int c = (i < N) ? cnt[i] : 0;
    s[t] = c;
    __syncthreads();
    for (int off = 1; off < 256; off <<= 1) {
        int v = (t >= off) ? s[t - off] : 0;
        __syncthreads();
        s[t] += v;
        __syncthreads();
    }
    if (i < N) row_ptr[i] = blockoff[blockIdx.x] + s[t] - c;
    if (i == 0) row_ptr[N] = E;
}

// ---------------- phase 2b: in-bucket counting sort -> csr ----------------
__global__ __launch_bounds__(256) void k_p2b(const unsigned* __restrict__ packed,
                                             const int* __restrict__ bucket_cursor,
                                             const int* __restrict__ row_ptr,
                                             int* __restrict__ csr, int N) {
    __shared__ int c512[512], cur512[512], sscan[256];
    int t = threadIdx.x, b = blockIdx.x;
    c512[t] = 0; c512[t + 256] = 0;
    __syncthreads();
    int m = bucket_cursor[b];
    const unsigned* pb = packed + (size_t)b * BCAP;
    for (int i = t; i < m; i += 256) atomicAdd(&c512[pb[i] >> 17], 1);
    __syncthreads();
    int v0 = c512[2 * t], v1 = c512[2 * t + 1];
    int ps = v0 + v1;
    sscan[t] = ps;
    __syncthreads();
    for (int off = 1; off < 256; off <<= 1) {
        int v = (t >= off) ? sscan[t - off] : 0;
        __syncthreads();
        sscan[t] += v;
        __syncthreads();
    }
    int excl = sscan[t] - ps;
    cur512[2 * t] = excl;
    cur512[2 * t + 1] = excl + v0;
    __syncthreads();
    int rbase = row_ptr[b << 9];
    for (int i = t; i < m; i += 256) {
        unsigned p = pb[i];
        int dl = p >> 17;
        int src = (int)(p & 0x1FFFFu);
        int pos = atomicAdd(&cur512[dl], 1);
        csr[rbase + pos] = src;
    }
}

// ---------------- MFMA GEMM: Th[N,128] = fp16( dinv[r] * (X @ W) ) ----------------
// Swapped operands: A := W^T (hoisted per-wave, 32 cols), B := X^T from an LDS-staged
// 64-row fp16 tile (each row staged ONCE per block; waves share it via ds_read).
// Frag maps (16x16x32): A: lane -> A[l&15][(l>>4)*8+j]; B: B[(l>>4)*8+j][l&15];
// D: row=(l>>4)*4+reg, col=l&15.
template <typename TIN>
__global__ __launch_bounds__(256) void k_gemm_mfma(const TIN* __restrict__ X,
                                                   const float* __restrict__ W,
                                                   const float* __restrict__ dinv,
                                                   _Float16* __restrict__ Th,
                                                   int N, int nRB) {
    __shared__ _Float16 Xs[64 * XS_LD];
    int t = threadIdx.x;
    int w = t >> 6;          // wave 0..3 -> cols [w*32, w*32+32)
    int l = t & 63;
    int l16 = l & 15;
    int lq = l >> 4;         // 0..3

    // Hoist A-frags = W^T for this wave's 32 cols
    f16x8 afrag[2][4];
#pragma unroll
    for (int ct = 0; ct < 2; ++ct) {
        int c = w * 32 + ct * 16 + l16;
#pragma unroll
        for (int kb = 0; kb < 4; ++kb) {
            f16x8 a;
#pragma unroll
            for (int j = 0; j < 8; ++j)
                a[j] = (_Float16)W[(kb * 32 + lq * 8 + j) * DHID + c];
            afrag[ct][kb] = a;
        }
    }

    int rs = t >> 2;          // staging: row 0..63
    int cs = (t & 3) * 32;    // staging: col block

    for (int rb = blockIdx.x; rb < nRB; rb += gridDim.x) {
        int r0 = rb * 64;
        {   // stage 64 rows x 128 cols as fp16 into LDS (convert if fp32 input)
            int rg = r0 + rs; if (rg > N - 1) rg = N - 1;
            _Float16* sp = Xs + rs * XS_LD + cs;
            if constexpr (sizeof(TIN) == 4) {
                const float* xp = (const float*)X + (size_t)rg * DHID + cs;
#pragma unroll
                for (int k = 0; k < 4; ++k) {
                    float4 a = *(const float4*)(xp + k * 8);
                    float4 b = *(const float4*)(xp + k * 8 + 4);
                    h8 v;
                    v[0] = (_Float16)a.x; v[1] = (_Float16)a.y;
                    v[2] = (_Float16)a.z; v[3] = (_Float16)a.w;
                    v[4] = (_Float16)b.x; v[5] = (_Float16)b.y;
                    v[6] = (_Float16)b.z; v[7] = (_Float16)b.w;
                    *(h8*)(sp + k * 8) = v;
                }
            } else {
                const _Float16* xp = (const _Float16*)X + (size_t)rg * DHID + cs;
#pragma unroll
                for (int k = 0; k < 4; ++k)
                    *(h8*)(sp + k * 8) = *(const h8*)(xp + k * 8);
            }
        }
        __syncthreads();

        f32x4 acc[4][2];
#pragma unroll
        for (int rt = 0; rt < 4; ++rt)
#pragma unroll
            for (int ct = 0; ct < 2; ++ct) acc[rt][ct] = (f32x4){0.f, 0.f, 0.f, 0.f};

#pragma unroll
        for (int rt = 0; rt < 4; ++rt) {
            const _Float16* bp = Xs + (rt * 16 + l16) * XS_LD + lq * 8;
#pragma unroll
            for (int kb = 0; kb < 4; ++kb) {
                f16x8 b = *(const f16x8*)(bp + kb * 32);
                acc[rt][0] = __builtin_amdgcn_mfma_f32_16x16x32_f16(afrag[0][kb], b, acc[rt][0], 0, 0, 0);
                acc[rt][1] = __builtin_amdgcn_mfma_f32_16x16x32_f16(afrag[1][kb], b, acc[rt][1], 0, 0, 0);
            }
        }
        __syncthreads();   // all ds_reads done before next stage overwrites

#pragma unroll
        for (int rt = 0; rt < 4; ++rt) {
            int r = r0 + rt * 16 + l16;
            if (r < N) {
                float s = dinv[r];
#pragma unroll
                for (int ct = 0; ct < 2; ++ct) {
                    h4 v;
#pragma unroll
                    for (int j = 0; j < 4; ++j) v[j] = (_Float16)(acc[rt][ct][j] * s);
                    *(h4*)(Th + (size_t)r * DHID + w * 32 + ct * 16 + lq * 4) = v;
                }
            }
        }
    }
}

// ---------------- aggregation: XCD-sliced columns ----------------
// Block b: slice = b&7 (16 cols), chunk = b>>3 (32 nodes). With round-robin
// blockIdx->XCD dispatch, each XCD's gather working set = N*16*2B = 3.2MB -> L2-resident.
// 8 lanes per node x h2 (4B) per lane. Th rows pre-scaled by dinv[src].
// FINAL=0: write fp16 H slice. FINAL=1: partial dot with Wl -> Ppart[slice*N+node].
template <int FINAL>
__global__ __launch_bounds__(256) void k_agg_slice(const _Float16* __restrict__ Th,
                                                   const int* __restrict__ row_ptr,
                                                   const int* __restrict__ csr_src,
                                                   const float* __restrict__ dinv,
                                                   const float* __restrict__ bias,
                                                   _Float16* __restrict__ H,
                                                   const float* __restrict__ Wl,
                                                   float* __restrict__ Ppart, int N) {
    int slice = blockIdx.x & 7;
    int chunk = blockIdx.x >> 3;
    int g  = threadIdx.x >> 3;        // 0..31 node group
    int l8 = threadIdx.x & 7;         // lane in group
    int node = chunk * 32 + g;
    if (node >= N) return;

    int e = row_ptr[node];
    int end = row_ptr[node + 1];
    const h2* Tl = (const h2*)Th + slice * 8 + l8;   // row r at Tl[r*64]

    float ax = 0.f, ay = 0.f;
    for (; e + 4 <= end; e += 4) {
        int s0 = csr_src[e];
        int s1 = csr_src[e + 1];
        int s2 = csr_src[e + 2];
        int s3 = csr_src[e + 3];
        h2 v0 = Tl[(size_t)s0 * 64];
        h2 v1 = Tl[(size_t)s1 * 64];
        h2 v2 = Tl[(size_t)s2 * 64];
        h2 v3 = Tl[(size_t)s3 * 64];
        ax += ((float)v0.x + (float)v1.x) + ((float)v2.x + (float)v3.x);
        ay += ((float)v0.y + (float)v1.y) + ((float)v2.y + (float)v3.y);
    }
    for (; e < end; ++e) {
        int s0 = csr_src[e];
        h2 v = Tl[(size_t)s0 * 64];
        ax += (float)v.x;
        ay += (float)v.y;
    }

    {   // self-loop (Th already dinv-scaled)
        h2 tv = Tl[(size_t)node * 64];
        ax += (float)tv.x;
        ay += (float)tv.y;
    }

    float dn = dinv[node];
    float2 b = *(const float2*)(bias + slice * 16 + l8 * 2);
    float r0 = fmaxf(fmaf(dn, ax, b.x), 0.f);
    float r1 = fmaxf(fmaf(dn, ay, b.y), 0.f);

    if (FINAL == 0) {
        h2 v; v.x = (_Float16)r0; v.y = (_Float16)r1;
        *(h2*)(H + (size_t)node * DHID + slice * 16 + l8 * 2) = v;
    } else {
        float2 wl = *(const float2*)(Wl + slice * 16 + l8 * 2);
        float p = fmaf(r0, wl.x, r1 * wl.y);
        p += __shfl_down(p, 4, 8);
        p += __shfl_down(p, 2, 8);
        p += __shfl_down(p, 1, 8);
        if (l8 == 0) Ppart[(size_t)slice * N + node] = p;
    }
}

// out[i] = sum_slices Ppart[s][i] + bl  (deterministic, no atomics)
__global__ void k_out_reduce(const float* __restrict__ Ppart, const float* __restrict__ bl,
                             float* __restrict__ out, int N) {
    int i = blockIdx.x * 256 + threadIdx.x;
    if (i < N) {
        float s = bl[0];
#pragma unroll
        for (int k = 0; k < 8; ++k) s += Ppart[(size_t)k * N + i];
        out[i] = s;
    }
}

// ---------------- launch ----------------
extern "C" void kernel_launch(void* const* d_in, const int* in_sizes, int n_in,
                              void* d_out, int out_size, void* d_ws, size_t ws_size,
                              hipStream_t stream) {
    const float* x  = (const float*)d_in[0];
    const int*   ei = (const int*)d_in[1];
    const float* W1 = (const float*)d_in[2];
    const float* b1 = (const float*)d_in[3];
    const float* W2 = (const float*)d_in[4];
    const float* b2 = (const float*)d_in[5];
    const float* Wl = (const float*)d_in[6];
    const float* bl = (const float*)d_in[7];
    float* out = (float*)d_out;

    int N = in_sizes[0] / DHID;     // 100000
    int E = in_sizes[1] / 2;        // 1600000
    int NB = (N + 255) / 256;       // 391
    int nbuck = (N + 511) / 512;    // 196
    int nRB = (N + 63) / 64;        // 1563
    int nchunk = (N + 31) / 32;     // 3125

    char* ws = (char*)d_ws;
    size_t off = 0;
    auto alloc = [&](size_t bytes) -> void* {
        void* p = ws + off;
        off += (bytes + 255) & ~(size_t)255;
        return p;
    };
    int*      cnt      = (int*)alloc((size_t)N * 4);
    float*    dinv     = (float*)alloc((size_t)N * 4);
    int*      row_ptr  = (int*)alloc((size_t)(N + 1) * 4);
    int*      partial  = (int*)alloc((size_t)NB * 4);
    int*      blockoff = (int*)alloc((size_t)NB * 4);
    int*      bcur     = (int*)alloc((size_t)nbuck * 4);
    int*      csr      = (int*)alloc((size_t)E * 4);
    unsigned* packed   = (unsigned*)alloc((size_t)nbuck * BCAP * 4);
    _Float16* Th       = (_Float16*)alloc((size_t)N * DHID * 2);
    _Float16* H        = (_Float16*)alloc((size_t)N * DHID * 2);
    float*    Ppart    = (float*)alloc((size_t)8 * N * 4);

    // ---- CSR build (bucketed counting sort; reused by both layers) ----
    (void)hipMemsetAsync(bcur, 0, (size_t)nbuck * 4, stream);
    k_partition<<<(E + PCHUNK - 1) / PCHUNK, 256, 0, stream>>>(ei, E, nbuck, bcur, packed);
    k_p2a<<<nbuck, 256, 0, stream>>>(packed, bcur, cnt, N);
    k_dinv<<<NB, 256, 0, stream>>>(cnt, dinv, N);
    k_reduce<<<NB, 256, 0, stream>>>(cnt, partial, N);
    k_scan_partials<<<1, 1024, 0, stream>>>(partial, blockoff, NB);
    k_scan_block<<<NB, 256, 0, stream>>>(cnt, blockoff, row_ptr, N, E);
    k_p2b<<<nbuck, 256, 0, stream>>>(packed, bcur, row_ptr, csr, N);

    // ---- layer 1 ----
    k_gemm_mfma<float><<<1024, 256, 0, stream>>>(x, W1, dinv, Th, N, nRB);
    k_agg_slice<0><<<nchunk * 8, 256, 0, stream>>>(Th, row_ptr, csr, dinv, b1, H, nullptr, nullptr, N);

    // ---- layer 2 + fused final projection ----
    k_gemm_mfma<_Float16><<<1024, 256, 0, stream>>>(H, W2, dinv, Th, N, nRB);
    k_agg_slice<1><<<nchunk * 8, 256, 0, stream>>>(Th, row_ptr, csr, dinv, b2, nullptr, Wl, Ppart, N);
    k_out_reduce<<<NB, 256, 0, stream>>>(Ppart, bl, out, N);
}

// Round 8
// 229.803 us; speedup vs baseline: 2.1130x; 2.1130x over previous
//
#include <hip/hip_runtime.h>

#define DHID 128
#define BCAP 10240         // per-bucket capacity (mean 8163, 23 sigma)
#define PCHUNK 4096        // edges per partition block
#define XS_LD 136          // LDS row stride in fp16 elems (128 + 8 pad)

typedef _Float16 h4 __attribute__((ext_vector_type(4)));
typedef _Float16 h8 __attribute__((ext_vector_type(8)));
typedef _Float16 f16x8 __attribute__((ext_vector_type(8)));
typedef float    f32x4 __attribute__((ext_vector_type(4)));

// ---------------- phase 1: partition edges into 512-node buckets ----------------
// packed entry: (dst & 511) << 17 | src   (src < 2^17)
__global__ __launch_bounds__(256) void k_partition(const int* __restrict__ ei, int E, int nbuck,
                                                   int* __restrict__ bucket_cursor,
                                                   unsigned* __restrict__ packed) {
    __shared__ unsigned sdata[PCHUNK];
    __shared__ int lcnt[256], lbase[256], loff[256], lcur[256], sscan[256];
    int t = threadIdx.x;
    int e0 = blockIdx.x * PCHUNK;
    lcnt[t] = 0;
    __syncthreads();

    for (int i = t; i < PCHUNK; i += 256) {
        int e = e0 + i;
        if (e < E) {
            int d = ei[E + e];
            atomicAdd(&lcnt[d >> 9], 1);
        }
    }
    __syncthreads();

    int c = lcnt[t];
    sscan[t] = c;
    __syncthreads();
    for (int off = 1; off < 256; off <<= 1) {
        int v = (t >= off) ? sscan[t - off] : 0;
        __syncthreads();
        sscan[t] += v;
        __syncthreads();
    }
    loff[t] = sscan[t] - c;
    if (t < nbuck && c > 0) lbase[t] = atomicAdd(&bucket_cursor[t], c);
    lcur[t] = sscan[t] - c;
    __syncthreads();

    for (int i = t; i < PCHUNK; i += 256) {
        int e = e0 + i;
        if (e < E) {
            int s = ei[e];
            int d = ei[E + e];
            int b = d >> 9;
            int pos = atomicAdd(&lcur[b], 1);
            sdata[pos] = ((unsigned)(d & 511) << 17) | (unsigned)s;
        }
    }
    __syncthreads();

    int wid = t >> 6, lane = t & 63;
    for (int b = wid; b < nbuck; b += 4) {
        int cb = lcnt[b];
        if (cb == 0) continue;
        int gbase = b * BCAP + lbase[b];
        int sbase = loff[b];
        for (int k = lane; k < cb; k += 64) packed[gbase + k] = sdata[sbase + k];
    }
}

// ---------------- phase 2a: per-node degree + dinv ----------------
__global__ __launch_bounds__(256) void k_p2a(const unsigned* __restrict__ packed,
                                             const int* __restrict__ bucket_cursor,
                                             int* __restrict__ cnt,
                                             float* __restrict__ dinv, int N) {
    __shared__ int c512[512];
    int t = threadIdx.x, b = blockIdx.x;
    c512[t] = 0; c512[t + 256] = 0;
    __syncthreads();
    int m = bucket_cursor[b];
    const unsigned* pb = packed + (size_t)b * BCAP;
    for (int i = t; i < m; i += 256) atomicAdd(&c512[pb[i] >> 17], 1);
    __syncthreads();
    int base = b << 9;
#pragma unroll
    for (int j = 0; j < 2; ++j) {
        int node = base + t + j * 256;
        if (node < N) {
            int c = c512[t + j * 256];
            cnt[node] = c;
            dinv[node] = rsqrtf((float)(c + 1));   // +1 self-loop
        }
    }
}

__global__ void k_reduce(const int* __restrict__ cnt, int* __restrict__ partial, int N) {
    __shared__ int s[256];
    int t = threadIdx.x;
    int i = blockIdx.x * 256 + t;
    s[t] = (i < N) ? cnt[i] : 0;
    __syncthreads();
    for (int st = 128; st > 0; st >>= 1) {
        if (t < st) s[t] += s[t + st];
        __syncthreads();
    }
    if (t == 0) partial[blockIdx.x] = s[0];
}

__global__ void k_scan_partials(const int* __restrict__ partial, int* __restrict__ blockoff, int NB) {
    __shared__ int s[1024];
    int t = threadIdx.x;
    s[t] = (t < NB) ? partial[t] : 0;
    __syncthreads();
    for (int off = 1; off < 1024; off <<= 1) {
        int v = (t >= off) ? s[t - off] : 0;
        __syncthreads();
        s[t] += v;
        __syncthreads();
    }
    if (t < NB) blockoff[t] = (t == 0) ? 0 : s[t - 1];
}

__global__ void k_scan_block(const int* __restrict__ cnt, const int* __restrict__ blockoff,
                             int* __restrict__ row_ptr, int N, int E) {
    __shared__ int s[256];
    int t = threadIdx.x;
    int i = blockIdx.x * 256 + t;
    int c = (i < N) ? cnt[i] : 0;
    s[t] = c;
    __syncthreads();
    for (int off = 1; off < 256; off <<= 1) {
        int v = (t >= off) ? s[t - off] : 0;
        __syncthreads();
        s[t] += v;
        __syncthreads();
    }
    if (i < N) row_ptr[i] = blockoff[blockIdx.x] + s[t] - c;
    if (i == 0) row_ptr[N] = E;
}

// ---------------- phase 2b: in-bucket counting sort -> csr ----------------
__global__ __launch_bounds__(256) void k_p2b(const unsigned* __restrict__ packed,
                                             const int* __restrict__ bucket_cursor,
                                             const int* __restrict__ row_ptr,
                                             int* __restrict__ csr, int N) {
    __shared__ int c512[512], cur512[512], sscan[256];
    int t = threadIdx.x, b = blockIdx.x;
    c512[t] = 0; c512[t + 256] = 0;
    __syncthreads();
    int m = bucket_cursor[b];
    const unsigned* pb = packed + (size_t)b * BCAP;
    for (int i = t; i < m; i += 256) atomicAdd(&c512[pb[i] >> 17], 1);
    __syncthreads();
    int v0 = c512[2 * t], v1 = c512[2 * t + 1];
    int ps = v0 + v1;
    sscan[t] = ps;
    __syncthreads();
    for (int off = 1; off < 256; off <<= 1) {
        int v = (t >= off) ? sscan[t - off] : 0;
        __syncthreads();
        sscan[t] += v;
        __syncthreads();
    }
    int excl = sscan[t] - ps;
    cur512[2 * t] = excl;
    cur512[2 * t + 1] = excl + v0;
    __syncthreads();
    int rbase = row_ptr[b << 9];
    for (int i = t; i < m; i += 256) {
        unsigned p = pb[i];
        int dl = p >> 17;
        int src = (int)(p & 0x1FFFFu);
        int pos = atomicAdd(&cur512[dl], 1);
        csr[rbase + pos] = src;
    }
}

// ---------------- MFMA GEMM: Th[N,128] = fp16( dinv[r] * (X @ W) ) ----------------
// Swapped operands: A := W^T (hoisted per-wave, 32 cols), B := X^T from an LDS-staged
// 64-row fp16 tile (each row staged ONCE per block; 4 waves share via ds_read).
// Grid = nRB blocks, one 64-row tile each (perfect balance; no grid-stride tail).
// Frag maps (16x16x32): A: lane -> A[l&15][(l>>4)*8+j]; B: B[(l>>4)*8+j][l&15];
// D: row=(l>>4)*4+reg, col=l&15.
template <typename TIN>
__global__ __launch_bounds__(256) void k_gemm_mfma(const TIN* __restrict__ X,
                                                   const float* __restrict__ W,
                                                   const float* __restrict__ dinv,
                                                   _Float16* __restrict__ Th, int N) {
    __shared__ _Float16 Xs[64 * XS_LD];
    int t = threadIdx.x;
    int w = t >> 6;          // wave 0..3 -> cols [w*32, w*32+32)
    int l = t & 63;
    int l16 = l & 15;
    int lq = l >> 4;         // 0..3

    // Hoist A-frags = W^T for this wave's 32 cols
    f16x8 afrag[2][4];
#pragma unroll
    for (int ct = 0; ct < 2; ++ct) {
        int c = w * 32 + ct * 16 + l16;
#pragma unroll
        for (int kb = 0; kb < 4; ++kb) {
            f16x8 a;
#pragma unroll
            for (int j = 0; j < 8; ++j)
                a[j] = (_Float16)W[(kb * 32 + lq * 8 + j) * DHID + c];
            afrag[ct][kb] = a;
        }
    }

    int rs = t >> 2;          // staging: row 0..63
    int cs = (t & 3) * 32;    // staging: col block

    int r0 = blockIdx.x * 64;
    {   // stage 64 rows x 128 cols as fp16 into LDS (convert if fp32 input)
        int rg = r0 + rs; if (rg > N - 1) rg = N - 1;
        _Float16* sp = Xs + rs * XS_LD + cs;
        if constexpr (sizeof(TIN) == 4) {
            const float* xp = (const float*)X + (size_t)rg * DHID + cs;
#pragma unroll
            for (int k = 0; k < 4; ++k) {
                float4 a = *(const float4*)(xp + k * 8);
                float4 b = *(const float4*)(xp + k * 8 + 4);
                h8 v;
                v[0] = (_Float16)a.x; v[1] = (_Float16)a.y;
                v[2] = (_Float16)a.z; v[3] = (_Float16)a.w;
                v[4] = (_Float16)b.x; v[5] = (_Float16)b.y;
                v[6] = (_Float16)b.z; v[7] = (_Float16)b.w;
                *(h8*)(sp + k * 8) = v;
            }
        } else {
            const _Float16* xp = (const _Float16*)X + (size_t)rg * DHID + cs;
#pragma unroll
            for (int k = 0; k < 4; ++k)
                *(h8*)(sp + k * 8) = *(const h8*)(xp + k * 8);
        }
    }
    __syncthreads();

    f32x4 acc[4][2];
#pragma unroll
    for (int rt = 0; rt < 4; ++rt)
#pragma unroll
        for (int ct = 0; ct < 2; ++ct) acc[rt][ct] = (f32x4){0.f, 0.f, 0.f, 0.f};

#pragma unroll
    for (int rt = 0; rt < 4; ++rt) {
        const _Float16* bp = Xs + (rt * 16 + l16) * XS_LD + lq * 8;
#pragma unroll
        for (int kb = 0; kb < 4; ++kb) {
            f16x8 b = *(const f16x8*)(bp + kb * 32);
            acc[rt][0] = __builtin_amdgcn_mfma_f32_16x16x32_f16(afrag[0][kb], b, acc[rt][0], 0, 0, 0);
            acc[rt][1] = __builtin_amdgcn_mfma_f32_16x16x32_f16(afrag[1][kb], b, acc[rt][1], 0, 0, 0);
        }
    }

#pragma unroll
    for (int rt = 0; rt < 4; ++rt) {
        int r = r0 + rt * 16 + l16;
        if (r < N) {
            float s = dinv[r];
#pragma unroll
            for (int ct = 0; ct < 2; ++ct) {
                h4 v;
#pragma unroll
                for (int j = 0; j < 4; ++j) v[j] = (_Float16)(acc[rt][ct][j] * s);
                *(h4*)(Th + (size_t)r * DHID + w * 32 + ct * 16 + lq * 4) = v;
            }
        }
    }
}

// ---------------- aggregation: 4 nodes per wave, 16 lanes x h8 per node --------
// Full-row gathers (line-optimal for random access; sub-line slicing loses — R7 lesson).
// Th rows pre-scaled by dinv[src].  res = relu(dinv[node]*(sum Th[src] + Th[node]) + b)
// FINAL=0: store res as fp16 H.  FINAL=1: fuse res @ Wl + bl (16-lane reduce).
template <int FINAL>
__global__ __launch_bounds__(256) void k_agg(const _Float16* __restrict__ Th,
                                             const int* __restrict__ row_ptr,
                                             const int* __restrict__ csr_src,
                                             const float* __restrict__ dinv,
                                             const float* __restrict__ bias,
                                             void* __restrict__ outp,
                                             const float* __restrict__ Wl,
                                             const float* __restrict__ bl, int N) {
    int node = blockIdx.x * 16 + (threadIdx.x >> 4);
    int sl = threadIdx.x & 15;
    if (node >= N) return;

    int e = row_ptr[node];
    int end = row_ptr[node + 1];
    const h8* Tl = (const h8*)Th + sl;        // row r at Tl[r*16]; 16B per lane

    float acc[8];
#pragma unroll
    for (int c = 0; c < 8; ++c) acc[c] = 0.f;

    for (; e + 4 <= end; e += 4) {
        int s0 = csr_src[e];
        int s1 = csr_src[e + 1];
        int s2 = csr_src[e + 2];
        int s3 = csr_src[e + 3];
        h8 v0 = Tl[(size_t)s0 * 16];
        h8 v1 = Tl[(size_t)s1 * 16];
        h8 v2 = Tl[(size_t)s2 * 16];
        h8 v3 = Tl[(size_t)s3 * 16];
#pragma unroll
        for (int c = 0; c < 8; ++c)
            acc[c] += ((float)v0[c] + (float)v1[c]) + ((float)v2[c] + (float)v3[c]);
    }
    for (; e < end; ++e) {
        int s0 = csr_src[e];
        h8 va = Tl[(size_t)s0 * 16];
#pragma unroll
        for (int c = 0; c < 8; ++c) acc[c] += (float)va[c];
    }

    {   // self-loop (Th already dinv-scaled)
        h8 tv = Tl[(size_t)node * 16];
#pragma unroll
        for (int c = 0; c < 8; ++c) acc[c] += (float)tv[c];
    }

    float dn = dinv[node];
    const float* bp = bias + sl * 8;
    float4 b0 = *(const float4*)bp;
    float4 b1 = *(const float4*)(bp + 4);
    float r[8];
    r[0] = fmaxf(fmaf(dn, acc[0], b0.x), 0.f);
    r[1] = fmaxf(fmaf(dn, acc[1], b0.y), 0.f);
    r[2] = fmaxf(fmaf(dn, acc[2], b0.z), 0.f);
    r[3] = fmaxf(fmaf(dn, acc[3], b0.w), 0.f);
    r[4] = fmaxf(fmaf(dn, acc[4], b1.x), 0.f);
    r[5] = fmaxf(fmaf(dn, acc[5], b1.y), 0.f);
    r[6] = fmaxf(fmaf(dn, acc[6], b1.z), 0.f);
    r[7] = fmaxf(fmaf(dn, acc[7], b1.w), 0.f);

    if (FINAL == 0) {
        h8 v;
#pragma unroll
        for (int c = 0; c < 8; ++c) v[c] = (_Float16)r[c];
        *(h8*)((_Float16*)outp + (size_t)node * DHID + sl * 8) = v;
    } else {
        const float* wp = Wl + sl * 8;
        float4 w0 = *(const float4*)wp;
        float4 w1 = *(const float4*)(wp + 4);
        float p = r[0] * w0.x + r[1] * w0.y + r[2] * w0.z + r[3] * w0.w +
                  r[4] * w1.x + r[5] * w1.y + r[6] * w1.z + r[7] * w1.w;
#pragma unroll
        for (int off = 8; off > 0; off >>= 1) p += __shfl_down(p, off, 16);
        if (sl == 0) ((float*)outp)[node] = p + bl[0];
    }
}

// ---------------- launch ----------------
extern "C" void kernel_launch(void* const* d_in, const int* in_sizes, int n_in,
                              void* d_out, int out_size, void* d_ws, size_t ws_size,
                              hipStream_t stream) {
    const float* x  = (const float*)d_in[0];
    const int*   ei = (const int*)d_in[1];
    const float* W1 = (const float*)d_in[2];
    const float* b1 = (const float*)d_in[3];
    const float* W2 = (const float*)d_in[4];
    const float* b2 = (const float*)d_in[5];
    const float* Wl = (const float*)d_in[6];
    const float* bl = (const float*)d_in[7];
    float* out = (float*)d_out;

    int N = in_sizes[0] / DHID;     // 100000
    int E = in_sizes[1] / 2;        // 1600000
    int NB = (N + 255) / 256;       // 391
    int nbuck = (N + 511) / 512;    // 196
    int nRB = (N + 63) / 64;        // 1563

    char* ws = (char*)d_ws;
    size_t off = 0;
    auto alloc = [&](size_t bytes) -> void* {
        void* p = ws + off;
        off += (bytes + 255) & ~(size_t)255;
        return p;
    };
    int*      cnt      = (int*)alloc((size_t)N * 4);
    float*    dinv     = (float*)alloc((size_t)N * 4);
    int*      row_ptr  = (int*)alloc((size_t)(N + 1) * 4);
    int*      partial  = (int*)alloc((size_t)NB * 4);
    int*      blockoff = (int*)alloc((size_t)NB * 4);
    int*      bcur     = (int*)alloc((size_t)nbuck * 4);
    int*      csr      = (int*)alloc((size_t)E * 4);
    unsigned* packed   = (unsigned*)alloc((size_t)nbuck * BCAP * 4);
    _Float16* Th       = (_Float16*)alloc((size_t)N * DHID * 2);
    _Float16* H        = (_Float16*)alloc((size_t)N * DHID * 2);

    // ---- CSR build (bucketed counting sort; reused by both layers) ----
    (void)hipMemsetAsync(bcur, 0, (size_t)nbuck * 4, stream);
    k_partition<<<(E + PCHUNK - 1) / PCHUNK, 256, 0, stream>>>(ei, E, nbuck, bcur, packed);
    k_p2a<<<nbuck, 256, 0, stream>>>(packed, bcur, cnt, dinv, N);
    k_reduce<<<NB, 256, 0, stream>>>(cnt, partial, N);
    k_scan_partials<<<1, 1024, 0, stream>>>(partial, blockoff, NB);
    k_scan_block<<<NB, 256, 0, stream>>>(cnt, blockoff, row_ptr, N, E);
    k_p2b<<<nbuck, 256, 0, stream>>>(packed, bcur, row_ptr, csr, N);

    // ---- layer 1 ----
    k_gemm_mfma<float><<<nRB, 256, 0, stream>>>(x, W1, dinv, Th, N);
    k_agg<0><<<(N + 15) / 16, 256, 0, stream>>>(Th, row_ptr, csr, dinv, b1, H, nullptr, nullptr, N);

    // ---- layer 2 + fused final projection ----
    k_gemm_mfma<_Float16><<<nRB, 256, 0, stream>>>(H, W2, dinv, Th, N);
    k_agg<1><<<(N + 15) / 16, 256, 0, stream>>>(Th, row_ptr, csr, dinv, b2, out, Wl, bl, N);
}

// Round 9
// 214.127 us; speedup vs baseline: 2.2677x; 1.0732x over previous
//
#include <hip/hip_runtime.h>

#define DHID 128
#define BCAP 10240         // per-bucket capacity (mean 8163, 23 sigma)
#define PCHUNK 4096        // edges per partition block
#define XS_LD 136          // LDS row stride in fp16 elems (128 + 8 pad -> 2-way banks)

typedef _Float16 h4 __attribute__((ext_vector_type(4)));
typedef _Float16 h8 __attribute__((ext_vector_type(8)));
typedef _Float16 f16x8 __attribute__((ext_vector_type(8)));
typedef float    f32x4 __attribute__((ext_vector_type(4)));

// ---------------- phase 1: partition edges into 512-node buckets ----------------
// packed entry: (dst & 511) << 17 | src   (src < 2^17)
// Edges held in registers across both passes (single read of ei).
__global__ __launch_bounds__(256) void k_partition(const int* __restrict__ ei, int E, int nbuck,
                                                   int* __restrict__ bucket_cursor,
                                                   unsigned* __restrict__ packed) {
    __shared__ unsigned sdata[PCHUNK];
    __shared__ int lcnt[256], lbase[256], loff[256], lcur[256], sscan[256];
    int t = threadIdx.x;
    int e0 = blockIdx.x * PCHUNK;
    lcnt[t] = 0;
    __syncthreads();

    int sreg[16], dreg[16];
#pragma unroll
    for (int k = 0; k < 16; ++k) {
        int e = e0 + t + k * 256;
        if (e < E) {
            sreg[k] = ei[e];
            dreg[k] = ei[E + e];
        } else {
            dreg[k] = -1;
        }
    }

    // pass A: count per bucket
#pragma unroll
    for (int k = 0; k < 16; ++k)
        if (dreg[k] >= 0) atomicAdd(&lcnt[dreg[k] >> 9], 1);
    __syncthreads();

    // exclusive scan of lcnt -> LDS segment layout; reserve global space per bucket
    int c = lcnt[t];
    sscan[t] = c;
    __syncthreads();
    for (int off = 1; off < 256; off <<= 1) {
        int v = (t >= off) ? sscan[t - off] : 0;
        __syncthreads();
        sscan[t] += v;
        __syncthreads();
    }
    loff[t] = sscan[t] - c;
    if (t < nbuck && c > 0) lbase[t] = atomicAdd(&bucket_cursor[t], c);
    lcur[t] = sscan[t] - c;
    __syncthreads();

    // pass B: scatter packed entries into LDS, grouped by bucket
#pragma unroll
    for (int k = 0; k < 16; ++k) {
        if (dreg[k] >= 0) {
            int b = dreg[k] >> 9;
            int pos = atomicAdd(&lcur[b], 1);
            sdata[pos] = ((unsigned)(dreg[k] & 511) << 17) | (unsigned)sreg[k];
        }
    }
    __syncthreads();

    // pass C: one wave per bucket, contiguous LDS segment -> global bucket region
    int wid = t >> 6, lane = t & 63;
    for (int b = wid; b < nbuck; b += 4) {
        int cb = lcnt[b];
        if (cb == 0) continue;
        int gbase = b * BCAP + lbase[b];
        int sbase = loff[b];
        for (int k = lane; k < cb; k += 64) packed[gbase + k] = sdata[sbase + k];
    }
}

// ---------------- bucket-total scan (1 block): bbase[b] = edges before bucket b ----
__global__ void k_bscan(const int* __restrict__ bcur, int* __restrict__ bbase,
                        int* __restrict__ row_ptr, int nbuck, int N, int E) {
    __shared__ int s[256];
    int t = threadIdx.x;
    int c = (t < nbuck) ? bcur[t] : 0;
    s[t] = c;
    __syncthreads();
    for (int off = 1; off < 256; off <<= 1) {
        int v = (t >= off) ? s[t - off] : 0;
        __syncthreads();
        s[t] += v;
        __syncthreads();
    }
    if (t <= nbuck) bbase[t] = (t == 0) ? 0 : s[t - 1];
    if (t == 0) row_ptr[N] = E;
}

// ---------------- phase 2: per-bucket counting sort -> row_ptr, dinv, csr ----------
// In-LDS node counts give degree (dinv), exclusive scan gives row_ptr, then the
// scatter is confined to this bucket's own ~32KB csr segment (L2-resident).
__global__ __launch_bounds__(256) void k_p2b(const unsigned* __restrict__ packed,
                                             const int* __restrict__ bucket_cursor,
                                             const int* __restrict__ bbase,
                                             int* __restrict__ row_ptr,
                                             float* __restrict__ dinv,
                                             int* __restrict__ csr, int N) {
    __shared__ int c512[512], cur512[512], sscan[256];
    int t = threadIdx.x, b = blockIdx.x;
    c512[t] = 0; c512[t + 256] = 0;
    __syncthreads();
    int m = bucket_cursor[b];
    const unsigned* pb = packed + (size_t)b * BCAP;
    for (int i = t; i < m; i += 256) atomicAdd(&c512[pb[i] >> 17], 1);
    __syncthreads();
    int v0 = c512[2 * t], v1 = c512[2 * t + 1];
    int ps = v0 + v1;
    sscan[t] = ps;
    __syncthreads();
    for (int off = 1; off < 256; off <<= 1) {
        int v = (t >= off) ? sscan[t - off] : 0;
        __syncthreads();
        sscan[t] += v;
        __syncthreads();
    }
    int excl = sscan[t] - ps;
    cur512[2 * t] = excl;
    cur512[2 * t + 1] = excl + v0;

    int rbase = bbase[b];
    int n0 = (b << 9) + 2 * t;
    if (n0 < N) {
        row_ptr[n0] = rbase + excl;
        dinv[n0] = rsqrtf((float)(v0 + 1));      // +1 self-loop
    }
    if (n0 + 1 < N) {
        row_ptr[n0 + 1] = rbase + excl + v0;
        dinv[n0 + 1] = rsqrtf((float)(v1 + 1));
    }
    __syncthreads();

    for (int i = t; i < m; i += 256) {
        unsigned p = pb[i];
        int dl = p >> 17;
        int src = (int)(p & 0x1FFFFu);
        int pos = atomicAdd(&cur512[dl], 1);
        csr[rbase + pos] = src;
    }
}

// ---------------- MFMA GEMM: Th[N,128] = fp16( dinv[r] * (X @ W) ) ----------------
// Swapped operands: A := W^T (hoisted per-wave, 32 cols), B := X^T from an LDS-staged
// 64-row fp16 tile (each row staged ONCE per block; 4 waves share via ds_read).
// Grid = nRB blocks, one 64-row tile each.
// Frag maps (16x16x32): A: lane -> A[l&15][(l>>4)*8+j]; B: B[(l>>4)*8+j][l&15];
// D: row=(l>>4)*4+reg, col=l&15.
template <typename TIN>
__global__ __launch_bounds__(256) void k_gemm_mfma(const TIN* __restrict__ X,
                                                   const float* __restrict__ W,
                                                   const float* __restrict__ dinv,
                                                   _Float16* __restrict__ Th, int N) {
    __shared__ _Float16 Xs[64 * XS_LD];
    int t = threadIdx.x;
    int w = t >> 6;          // wave 0..3 -> cols [w*32, w*32+32)
    int l = t & 63;
    int l16 = l & 15;
    int lq = l >> 4;         // 0..3

    // Hoist A-frags = W^T for this wave's 32 cols
    f16x8 afrag[2][4];
#pragma unroll
    for (int ct = 0; ct < 2; ++ct) {
        int c = w * 32 + ct * 16 + l16;
#pragma unroll
        for (int kb = 0; kb < 4; ++kb) {
            f16x8 a;
#pragma unroll
            for (int j = 0; j < 8; ++j)
                a[j] = (_Float16)W[(kb * 32 + lq * 8 + j) * DHID + c];
            afrag[ct][kb] = a;
        }
    }

    int rs = t >> 2;          // staging: row 0..63
    int cs = (t & 3) * 32;    // staging: col block

    int r0 = blockIdx.x * 64;
    {   // stage 64 rows x 128 cols as fp16 into LDS (convert if fp32 input)
        int rg = r0 + rs; if (rg > N - 1) rg = N - 1;
        _Float16* sp = Xs + rs * XS_LD + cs;
        if constexpr (sizeof(TIN) == 4) {
            const float* xp = (const float*)X + (size_t)rg * DHID + cs;
#pragma unroll
            for (int k = 0; k < 4; ++k) {
                float4 a = *(const float4*)(xp + k * 8);
                float4 b = *(const float4*)(xp + k * 8 + 4);
                h8 v;
                v[0] = (_Float16)a.x; v[1] = (_Float16)a.y;
                v[2] = (_Float16)a.z; v[3] = (_Float16)a.w;
                v[4] = (_Float16)b.x; v[5] = (_Float16)b.y;
                v[6] = (_Float16)b.z; v[7] = (_Float16)b.w;
                *(h8*)(sp + k * 8) = v;
            }
        } else {
            const _Float16* xp = (const _Float16*)X + (size_t)rg * DHID + cs;
#pragma unroll
            for (int k = 0; k < 4; ++k)
                *(h8*)(sp + k * 8) = *(const h8*)(xp + k * 8);
        }
    }
    __syncthreads();

    f32x4 acc[4][2];
#pragma unroll
    for (int rt = 0; rt < 4; ++rt)
#pragma unroll
        for (int ct = 0; ct < 2; ++ct) acc[rt][ct] = (f32x4){0.f, 0.f, 0.f, 0.f};

#pragma unroll
    for (int rt = 0; rt < 4; ++rt) {
        const _Float16* bp = Xs + (rt * 16 + l16) * XS_LD + lq * 8;
#pragma unroll
        for (int kb = 0; kb < 4; ++kb) {
            f16x8 b = *(const f16x8*)(bp + kb * 32);
            acc[rt][0] = __builtin_amdgcn_mfma_f32_16x16x32_f16(afrag[0][kb], b, acc[rt][0], 0, 0, 0);
            acc[rt][1] = __builtin_amdgcn_mfma_f32_16x16x32_f16(afrag[1][kb], b, acc[rt][1], 0, 0, 0);
        }
    }

#pragma unroll
    for (int rt = 0; rt < 4; ++rt) {
        int r = r0 + rt * 16 + l16;
        if (r < N) {
            float s = dinv[r];
#pragma unroll
            for (int ct = 0; ct < 2; ++ct) {
                h4 v;
#pragma unroll
                for (int j = 0; j < 4; ++j) v[j] = (_Float16)(acc[rt][ct][j] * s);
                *(h4*)(Th + (size_t)r * DHID + w * 32 + ct * 16 + lq * 4) = v;
            }
        }
    }
}

// ---------------- aggregation: 4 nodes per wave, 16 lanes x h8 per node --------
// Full-row gathers (line-optimal; sub-line slicing loses — R7). Service-rate-bound
// at ~3.6 TB/s L2-miss path (R8 Little's-law check) — structure frozen.
// Th rows pre-scaled by dinv[src].  res = relu(dinv[node]*(sum Th[src] + Th[node]) + b)
// FINAL=0: store res as fp16 H.  FINAL=1: fuse res @ Wl + bl (16-lane reduce).
template <int FINAL>
__global__ __launch_bounds__(256) void k_agg(const _Float16* __restrict__ Th,
                                             const int* __restrict__ row_ptr,
                                             const int* __restrict__ csr_src,
                                             const float* __restrict__ dinv,
                                             const float* __restrict__ bias,
                                             void* __restrict__ outp,
                                             const float* __restrict__ Wl,
                                             const float* __restrict__ bl, int N) {
    int node = blockIdx.x * 16 + (threadIdx.x >> 4);
    int sl = threadIdx.x & 15;
    if (node >= N) return;

    int e = row_ptr[node];
    int end = row_ptr[node + 1];
    const h8* Tl = (const h8*)Th + sl;        // row r at Tl[r*16]; 16B per lane

    float acc[8];
#pragma unroll
    for (int c = 0; c < 8; ++c) acc[c] = 0.f;

    for (; e + 4 <= end; e += 4) {
        int s0 = csr_src[e];
        int s1 = csr_src[e + 1];
        int s2 = csr_src[e + 2];
        int s3 = csr_src[e + 3];
        h8 v0 = Tl[(size_t)s0 * 16];
        h8 v1 = Tl[(size_t)s1 * 16];
        h8 v2 = Tl[(size_t)s2 * 16];
        h8 v3 = Tl[(size_t)s3 * 16];
#pragma unroll
        for (int c = 0; c < 8; ++c)
            acc[c] += ((float)v0[c] + (float)v1[c]) + ((float)v2[c] + (float)v3[c]);
    }
    for (; e < end; ++e) {
        int s0 = csr_src[e];
        h8 va = Tl[(size_t)s0 * 16];
#pragma unroll
        for (int c = 0; c < 8; ++c) acc[c] += (float)va[c];
    }

    {   // self-loop (Th already dinv-scaled)
        h8 tv = Tl[(size_t)node * 16];
#pragma unroll
        for (int c = 0; c < 8; ++c) acc[c] += (float)tv[c];
    }

    float dn = dinv[node];
    const float* bp = bias + sl * 8;
    float4 b0 = *(const float4*)bp;
    float4 b1 = *(const float4*)(bp + 4);
    float r[8];
    r[0] = fmaxf(fmaf(dn, acc[0], b0.x), 0.f);
    r[1] = fmaxf(fmaf(dn, acc[1], b0.y), 0.f);
    r[2] = fmaxf(fmaf(dn, acc[2], b0.z), 0.f);
    r[3] = fmaxf(fmaf(dn, acc[3], b0.w), 0.f);
    r[4] = fmaxf(fmaf(dn, acc[4], b1.x), 0.f);
    r[5] = fmaxf(fmaf(dn, acc[5], b1.y), 0.f);
    r[6] = fmaxf(fmaf(dn, acc[6], b1.z), 0.f);
    r[7] = fmaxf(fmaf(dn, acc[7], b1.w), 0.f);

    if (FINAL == 0) {
        h8 v;
#pragma unroll
        for (int c = 0; c < 8; ++c) v[c] = (_Float16)r[c];
        *(h8*)((_Float16*)outp + (size_t)node * DHID + sl * 8) = v;
    } else {
        const float* wp = Wl + sl * 8;
        float4 w0 = *(const float4*)wp;
        float4 w1 = *(const float4*)(wp + 4);
        float p = r[0] * w0.x + r[1] * w0.y + r[2] * w0.z + r[3] * w0.w +
                  r[4] * w1.x + r[5] * w1.y + r[6] * w1.z + r[7] * w1.w;
#pragma unroll
        for (int off = 8; off > 0; off >>= 1) p += __shfl_down(p, off, 16);
        if (sl == 0) ((float*)outp)[node] = p + bl[0];
    }
}

// ---------------- launch ----------------
extern "C" void kernel_launch(void* const* d_in, const int* in_sizes, int n_in,
                              void* d_out, int out_size, void* d_ws, size_t ws_size,
                              hipStream_t stream) {
    const float* x  = (const float*)d_in[0];
    const int*   ei = (const int*)d_in[1];
    const float* W1 = (const float*)d_in[2];
    const float* b1 = (const float*)d_in[3];
    const float* W2 = (const float*)d_in[4];
    const float* b2 = (const float*)d_in[5];
    const float* Wl = (const float*)d_in[6];
    const float* bl = (const float*)d_in[7];
    float* out = (float*)d_out;

    int N = in_sizes[0] / DHID;     // 100000
    int E = in_sizes[1] / 2;        // 1600000
    int nbuck = (N + 511) / 512;    // 196
    int nRB = (N + 63) / 64;        // 1563

    char* ws = (char*)d_ws;
    size_t off = 0;
    auto alloc = [&](size_t bytes) -> void* {
        void* p = ws + off;
        off += (bytes + 255) & ~(size_t)255;
        return p;
    };
    float*    dinv     = (float*)alloc((size_t)N * 4);
    int*      row_ptr  = (int*)alloc((size_t)(N + 1) * 4);
    int*      bcur     = (int*)alloc((size_t)nbuck * 4);
    int*      bbase    = (int*)alloc((size_t)(nbuck + 1) * 4);
    int*      csr      = (int*)alloc((size_t)E * 4);
    unsigned* packed   = (unsigned*)alloc((size_t)nbuck * BCAP * 4);
    _Float16* Th       = (_Float16*)alloc((size_t)N * DHID * 2);
    _Float16* H        = (_Float16*)alloc((size_t)N * DHID * 2);

    // ---- CSR build: partition -> bucket scan -> counting sort (row_ptr/dinv/csr) ----
    (void)hipMemsetAsync(bcur, 0, (size_t)nbuck * 4, stream);
    k_partition<<<(E + PCHUNK - 1) / PCHUNK, 256, 0, stream>>>(ei, E, nbuck, bcur, packed);
    k_bscan<<<1, 256, 0, stream>>>(bcur, bbase, row_ptr, nbuck, N, E);
    k_p2b<<<nbuck, 256, 0, stream>>>(packed, bcur, bbase, row_ptr, dinv, csr, N);

    // ---- layer 1 ----
    k_gemm_mfma<float><<<nRB, 256, 0, stream>>>(x, W1, dinv, Th, N);
    k_agg<0><<<(N + 15) / 16, 256, 0, stream>>>(Th, row_ptr, csr, dinv, b1, H, nullptr, nullptr, N);

    // ---- layer 2 + fused final projection ----
    k_gemm_mfma<_Float16><<<nRB, 256, 0, stream>>>(H, W2, dinv, Th, N);
    k_agg<1><<<(N + 15) / 16, 256, 0, stream>>>(Th, row_ptr, csr, dinv, b2, out, Wl, bl, N);
}

// Round 10
// 210.352 us; speedup vs baseline: 2.3084x; 1.0179x over previous
//
#include <hip/hip_runtime.h>

#define DHID 128
#define BCAP 10240         // per-bucket capacity (mean 8163, 23 sigma)
#define PCHUNK 4096        // edges per partition block
#define XS_LD 136          // LDS row stride in fp16 elems (128 + 8 pad)
#define SMEM_BYTES 21504   // union: partition 21504B > gemm 64*136*2=17408B

typedef _Float16 h4 __attribute__((ext_vector_type(4)));
typedef _Float16 h8 __attribute__((ext_vector_type(8)));
typedef float    f32x4 __attribute__((ext_vector_type(4)));

// ---- hoist A-frags = W^T for wave w (cols w*32..+31) from fp16 col-major Wt ----
// a[j] = W[k = kb*32+lq*8+j][c] = Wt[c*128 + k] -> contiguous h8 loads.
__device__ inline void hoist_afrag_f16(const _Float16* __restrict__ Wt, int w, int l16, int lq,
                                       h8 afrag[2][4]) {
#pragma unroll
    for (int ct = 0; ct < 2; ++ct) {
        int c = w * 32 + ct * 16 + l16;
#pragma unroll
        for (int kb = 0; kb < 4; ++kb)
            afrag[ct][kb] = *(const h8*)(Wt + (size_t)c * DHID + kb * 32 + lq * 8);
    }
}

// ---- gemm1 body: Th[N,128] = fp16(X @ W1), UNSCALED (dinv applied in agg) ----
// A := W1^T hoisted (scalar strided loads, W1 is fp32), B := X^T from LDS tile.
__device__ inline void gemm1_body(char* smem, const float* __restrict__ X,
                                  const float* __restrict__ W,
                                  _Float16* __restrict__ Th, int N, int blk) {
    _Float16* Xs = (_Float16*)smem;
    int t = threadIdx.x;
    int w = t >> 6, l = t & 63, l16 = l & 15, lq = l >> 4;

    h8 afrag[2][4];
#pragma unroll
    for (int ct = 0; ct < 2; ++ct) {
        int c = w * 32 + ct * 16 + l16;
#pragma unroll
        for (int kb = 0; kb < 4; ++kb) {
            h8 a;
#pragma unroll
            for (int j = 0; j < 8; ++j)
                a[j] = (_Float16)W[(kb * 32 + lq * 8 + j) * DHID + c];
            afrag[ct][kb] = a;
        }
    }

    int rs = t >> 2, cs = (t & 3) * 32;
    int r0 = blk * 64;
    {
        int rg = r0 + rs; if (rg > N - 1) rg = N - 1;
        _Float16* sp = Xs + rs * XS_LD + cs;
        const float* xp = X + (size_t)rg * DHID + cs;
#pragma unroll
        for (int k = 0; k < 4; ++k) {
            float4 a = *(const float4*)(xp + k * 8);
            float4 b = *(const float4*)(xp + k * 8 + 4);
            h8 v;
            v[0] = (_Float16)a.x; v[1] = (_Float16)a.y;
            v[2] = (_Float16)a.z; v[3] = (_Float16)a.w;
            v[4] = (_Float16)b.x; v[5] = (_Float16)b.y;
            v[6] = (_Float16)b.z; v[7] = (_Float16)b.w;
            *(h8*)(sp + k * 8) = v;
        }
    }
    __syncthreads();

    f32x4 acc[4][2];
#pragma unroll
    for (int rt = 0; rt < 4; ++rt)
#pragma unroll
        for (int ct = 0; ct < 2; ++ct) acc[rt][ct] = (f32x4){0.f, 0.f, 0.f, 0.f};

#pragma unroll
    for (int rt = 0; rt < 4; ++rt) {
        const _Float16* bp = Xs + (rt * 16 + l16) * XS_LD + lq * 8;
#pragma unroll
        for (int kb = 0; kb < 4; ++kb) {
            h8 b = *(const h8*)(bp + kb * 32);
            acc[rt][0] = __builtin_amdgcn_mfma_f32_16x16x32_f16(afrag[0][kb], b, acc[rt][0], 0, 0, 0);
            acc[rt][1] = __builtin_amdgcn_mfma_f32_16x16x32_f16(afrag[1][kb], b, acc[rt][1], 0, 0, 0);
        }
    }

#pragma unroll
    for (int rt = 0; rt < 4; ++rt) {
        int r = r0 + rt * 16 + l16;
        if (r < N) {
#pragma unroll
            for (int ct = 0; ct < 2; ++ct) {
                h4 v;
#pragma unroll
                for (int j = 0; j < 4; ++j) v[j] = (_Float16)acc[rt][ct][j];
                *(h4*)(Th + (size_t)r * DHID + w * 32 + ct * 16 + lq * 4) = v;
            }
        }
    }
}

// ---- partition body: bucket edges by dst>>9; packed entry (dst&511)<<17 | src ----
__device__ inline void partition_body(char* smem, const int* __restrict__ ei, int E, int nbuck,
                                      int* __restrict__ bcur, unsigned* __restrict__ packed, int blk) {
    unsigned* sdata = (unsigned*)smem;          // 16384 B
    int* lcnt  = (int*)(smem + 16384);
    int* lbase = (int*)(smem + 17408);
    int* loff  = (int*)(smem + 18432);
    int* lcur  = (int*)(smem + 19456);
    int* sscan = (int*)(smem + 20480);
    int t = threadIdx.x;
    int e0 = blk * PCHUNK;
    lcnt[t] = 0;
    __syncthreads();

    int sreg[16], dreg[16];
#pragma unroll
    for (int k = 0; k < 16; ++k) {
        int e = e0 + t + k * 256;
        if (e < E) { sreg[k] = ei[e]; dreg[k] = ei[E + e]; }
        else dreg[k] = -1;
    }

#pragma unroll
    for (int k = 0; k < 16; ++k)
        if (dreg[k] >= 0) atomicAdd(&lcnt[dreg[k] >> 9], 1);
    __syncthreads();

    int c = lcnt[t];
    sscan[t] = c;
    __syncthreads();
    for (int off = 1; off < 256; off <<= 1) {
        int v = (t >= off) ? sscan[t - off] : 0;
        __syncthreads();
        sscan[t] += v;
        __syncthreads();
    }
    loff[t] = sscan[t] - c;
    if (t < nbuck && c > 0) lbase[t] = atomicAdd(&bcur[t], c);
    lcur[t] = sscan[t] - c;
    __syncthreads();

#pragma unroll
    for (int k = 0; k < 16; ++k) {
        if (dreg[k] >= 0) {
            int b = dreg[k] >> 9;
            int pos = atomicAdd(&lcur[b], 1);
            sdata[pos] = ((unsigned)(dreg[k] & 511) << 17) | (unsigned)sreg[k];
        }
    }
    __syncthreads();

    int wid = t >> 6, lane = t & 63;
    for (int b = wid; b < nbuck; b += 4) {
        int cb = lcnt[b];
        if (cb == 0) continue;
        int gbase = b * BCAP + lbase[b];
        int sbase = loff[b];
        for (int k = lane; k < cb; k += 64) packed[gbase + k] = sdata[sbase + k];
    }
}

// ---- K1: gemm1 (blocks < nRB) || edge partition (blocks >= nRB) — independent work ----
__global__ __launch_bounds__(256) void k_front(const float* __restrict__ X,
                                               const float* __restrict__ W1,
                                               _Float16* __restrict__ Th, int N, int nRB,
                                               const int* __restrict__ ei, int E, int nbuck,
                                               int* __restrict__ bcur, unsigned* __restrict__ packed) {
    __shared__ __align__(16) char smem[SMEM_BYTES];
    if ((int)blockIdx.x < nRB)
        gemm1_body(smem, X, W1, Th, N, blockIdx.x);
    else
        partition_body(smem, ei, E, nbuck, bcur, packed, blockIdx.x - nRB);
}

// ---- K2: per-bucket counting sort -> row_ptr, dinv, csr (self-scans bucket totals);
//      block nbuck transposes W2 -> fp16 col-major W2t for K3's vectorized hoist ----
__global__ __launch_bounds__(256) void k_p2b(const unsigned* __restrict__ packed,
                                             const int* __restrict__ bcur,
                                             int* __restrict__ row_ptr,
                                             float* __restrict__ dinv,
                                             int* __restrict__ csr,
                                             const float* __restrict__ W2,
                                             _Float16* __restrict__ W2t,
                                             int nbuck, int N, int E) {
    int t = threadIdx.x, b = blockIdx.x;
    if (b == nbuck) {   // W2 transpose: W2t[c][k] = fp16(W2[k][c])
        int c = t & 127, k0 = (t >> 7) * 64;
#pragma unroll
        for (int kb = 0; kb < 8; ++kb) {
            h8 v;
#pragma unroll
            for (int j = 0; j < 8; ++j)
                v[j] = (_Float16)W2[(size_t)(k0 + kb * 8 + j) * DHID + c];
            *(h8*)(W2t + (size_t)c * DHID + k0 + kb * 8) = v;
        }
        return;
    }

    __shared__ int c512[512], cur512[512], sscan[256], sbk[256];
    sbk[t] = (t < nbuck) ? bcur[t] : 0;
    c512[t] = 0; c512[t + 256] = 0;
    __syncthreads();
    for (int off = 1; off < 256; off <<= 1) {   // inclusive scan of bucket totals
        int v = (t >= off) ? sbk[t - off] : 0;
        __syncthreads();
        sbk[t] += v;
        __syncthreads();
    }
    int rbase = (b > 0) ? sbk[b - 1] : 0;
    int m = bcur[b];
    const unsigned* pb = packed + (size_t)b * BCAP;
    for (int i = t; i < m; i += 256) atomicAdd(&c512[pb[i] >> 17], 1);
    __syncthreads();
    int v0 = c512[2 * t], v1 = c512[2 * t + 1];
    int ps = v0 + v1;
    sscan[t] = ps;
    __syncthreads();
    for (int off = 1; off < 256; off <<= 1) {
        int v = (t >= off) ? sscan[t - off] : 0;
        __syncthreads();
        sscan[t] += v;
        __syncthreads();
    }
    int excl = sscan[t] - ps;
    cur512[2 * t] = excl;
    cur512[2 * t + 1] = excl + v0;

    int n0 = (b << 9) + 2 * t;
    if (n0 < N) {
        row_ptr[n0] = rbase + excl;
        dinv[n0] = rsqrtf((float)(v0 + 1));     // +1 self-loop
    }
    if (n0 + 1 < N) {
        row_ptr[n0 + 1] = rbase + excl + v0;
        dinv[n0 + 1] = rsqrtf((float)(v1 + 1));
    }
    if (b == 0 && t == 0) row_ptr[N] = E;
    __syncthreads();

    for (int i = t; i < m; i += 256) {
        unsigned p = pb[i];
        int dl = p >> 17;
        int src = (int)(p & 0x1FFFFu);
        int pos = atomicAdd(&cur512[dl], 1);
        csr[rbase + pos] = src;
    }
}

// ---- K3: agg layer-1 + fused gemm2.  16 nodes/block, 16 lanes x h8 per node.
// acc = sum_e dinv[s]*Th[s] + dinv[n]*Th[n];  h = relu(dinv[n]*acc + b1) -> LDS tile;
// then 16x128 @ 128x128 MFMA with W2 -> Th2 (unscaled).  No early return (barrier!). ----
__global__ __launch_bounds__(256) void k_agg_gemm(const _Float16* __restrict__ Th,
                                                  const int* __restrict__ row_ptr,
                                                  const int* __restrict__ csr,
                                                  const float* __restrict__ dinv,
                                                  const float* __restrict__ bias,
                                                  const _Float16* __restrict__ W2t,
                                                  _Float16* __restrict__ Th2, int N) {
    __shared__ _Float16 Hs[16 * XS_LD];
    int t = threadIdx.x, w = t >> 6, l = t & 63, l16 = l & 15, lq = l >> 4;

    h8 afrag[2][4];
    hoist_afrag_f16(W2t, w, l16, lq, afrag);

    int g = t >> 4, sl = t & 15;
    int node = blockIdx.x * 16 + g;
    bool valid = node < N;
    int nc = valid ? node : N - 1;
    int e = row_ptr[nc];
    int end = row_ptr[nc + 1];
    if (!valid) end = e;
    const h8* Tl = (const h8*)Th + sl;

    float acc[8];
#pragma unroll
    for (int c = 0; c < 8; ++c) acc[c] = 0.f;

    for (; e + 4 <= end; e += 4) {
        int s0 = csr[e], s1 = csr[e + 1], s2 = csr[e + 2], s3 = csr[e + 3];
        float d0 = dinv[s0], d1 = dinv[s1], d2 = dinv[s2], d3 = dinv[s3];
        h8 v0 = Tl[(size_t)s0 * 16];
        h8 v1 = Tl[(size_t)s1 * 16];
        h8 v2 = Tl[(size_t)s2 * 16];
        h8 v3 = Tl[(size_t)s3 * 16];
#pragma unroll
        for (int c = 0; c < 8; ++c) {
            float a0 = fmaf(d0, (float)v0[c], fmaf(d1, (float)v1[c], 0.f));
            float a1 = fmaf(d2, (float)v2[c], fmaf(d3, (float)v3[c], 0.f));
            acc[c] += a0 + a1;
        }
    }
    for (; e < end; ++e) {
        int s0 = csr[e];
        float d0 = dinv[s0];
        h8 va = Tl[(size_t)s0 * 16];
#pragma unroll
        for (int c = 0; c < 8; ++c) acc[c] = fmaf(d0, (float)va[c], acc[c]);
    }

    float dn = valid ? dinv[nc] : 0.f;
    {   // self-loop
        h8 tv = Tl[(size_t)nc * 16];
#pragma unroll
        for (int c = 0; c < 8; ++c) acc[c] = fmaf(dn, (float)tv[c], acc[c]);
    }

    const float* bp = bias + sl * 8;
    float4 b0 = *(const float4*)bp;
    float4 b1 = *(const float4*)(bp + 4);
    h8 hv;
    hv[0] = (_Float16)fmaxf(fmaf(dn, acc[0], b0.x), 0.f);
    hv[1] = (_Float16)fmaxf(fmaf(dn, acc[1], b0.y), 0.f);
    hv[2] = (_Float16)fmaxf(fmaf(dn, acc[2], b0.z), 0.f);
    hv[3] = (_Float16)fmaxf(fmaf(dn, acc[3], b0.w), 0.f);
    hv[4] = (_Float16)fmaxf(fmaf(dn, acc[4], b1.x), 0.f);
    hv[5] = (_Float16)fmaxf(fmaf(dn, acc[5], b1.y), 0.f);
    hv[6] = (_Float16)fmaxf(fmaf(dn, acc[6], b1.z), 0.f);
    hv[7] = (_Float16)fmaxf(fmaf(dn, acc[7], b1.w), 0.f);
    *(h8*)(Hs + g * XS_LD + sl * 8) = hv;
    __syncthreads();

    // fused gemm2: D = (H16 @ W2)^T via swapped operands; lane l16 = node row
    f32x4 am[2] = {(f32x4){0.f, 0.f, 0.f, 0.f}, (f32x4){0.f, 0.f, 0.f, 0.f}};
#pragma unroll
    for (int kb = 0; kb < 4; ++kb) {
        h8 bfr = *(const h8*)(Hs + l16 * XS_LD + kb * 32 + lq * 8);
        am[0] = __builtin_amdgcn_mfma_f32_16x16x32_f16(afrag[0][kb], bfr, am[0], 0, 0, 0);
        am[1] = __builtin_amdgcn_mfma_f32_16x16x32_f16(afrag[1][kb], bfr, am[1], 0, 0, 0);
    }
    int rg = blockIdx.x * 16 + l16;
    if (rg < N) {
#pragma unroll
        for (int ct = 0; ct < 2; ++ct) {
            h4 v;
#pragma unroll
            for (int j = 0; j < 4; ++j) v[j] = (_Float16)am[ct][j];
            *(h4*)(Th2 + (size_t)rg * DHID + w * 32 + ct * 16 + lq * 4) = v;
        }
    }
}

// ---- K4: final agg + Wl projection.  Th2 unscaled -> per-edge dinv weights. ----
__global__ __launch_bounds__(256) void k_agg_fin(const _Float16* __restrict__ Th2,
                                                 const int* __restrict__ row_ptr,
                                                 const int* __restrict__ csr,
                                                 const float* __restrict__ dinv,
                                                 const float* __restrict__ bias,
                                                 const float* __restrict__ Wl,
                                                 const float* __restrict__ bl,
                                                 float* __restrict__ out, int N) {
    int node = blockIdx.x * 16 + (threadIdx.x >> 4);
    int sl = threadIdx.x & 15;
    if (node >= N) return;

    int e = row_ptr[node];
    int end = row_ptr[node + 1];
    const h8* Tl = (const h8*)Th2 + sl;

    float acc[8];
#pragma unroll
    for (int c = 0; c < 8; ++c) acc[c] = 0.f;

    for (; e + 4 <= end; e += 4) {
        int s0 = csr[e], s1 = csr[e + 1], s2 = csr[e + 2], s3 = csr[e + 3];
        float d0 = dinv[s0], d1 = dinv[s1], d2 = dinv[s2], d3 = dinv[s3];
        h8 v0 = Tl[(size_t)s0 * 16];
        h8 v1 = Tl[(size_t)s1 * 16];
        h8 v2 = Tl[(size_t)s2 * 16];
        h8 v3 = Tl[(size_t)s3 * 16];
#pragma unroll
        for (int c = 0; c < 8; ++c) {
            float a0 = fmaf(d0, (float)v0[c], fmaf(d1, (float)v1[c], 0.f));
            float a1 = fmaf(d2, (float)v2[c], fmaf(d3, (float)v3[c], 0.f));
            acc[c] += a0 + a1;
        }
    }
    for (; e < end; ++e) {
        int s0 = csr[e];
        float d0 = dinv[s0];
        h8 va = Tl[(size_t)s0 * 16];
#pragma unroll
        for (int c = 0; c < 8; ++c) acc[c] = fmaf(d0, (float)va[c], acc[c]);
    }

    float dn = dinv[node];
    {   // self-loop
        h8 tv = Tl[(size_t)node * 16];
#pragma unroll
        for (int c = 0; c < 8; ++c) acc[c] = fmaf(dn, (float)tv[c], acc[c]);
    }

    const float* bp = bias + sl * 8;
    float4 b0 = *(const float4*)bp;
    float4 b1 = *(const float4*)(bp + 4);
    float r[8];
    r[0] = fmaxf(fmaf(dn, acc[0], b0.x), 0.f);
    r[1] = fmaxf(fmaf(dn, acc[1], b0.y), 0.f);
    r[2] = fmaxf(fmaf(dn, acc[2], b0.z), 0.f);
    r[3] = fmaxf(fmaf(dn, acc[3], b0.w), 0.f);
    r[4] = fmaxf(fmaf(dn, acc[4], b1.x), 0.f);
    r[5] = fmaxf(fmaf(dn, acc[5], b1.y), 0.f);
    r[6] = fmaxf(fmaf(dn, acc[6], b1.z), 0.f);
    r[7] = fmaxf(fmaf(dn, acc[7], b1.w), 0.f);

    const float* wp = Wl + sl * 8;
    float4 w0 = *(const float4*)wp;
    float4 w1 = *(const float4*)(wp + 4);
    float p = r[0] * w0.x + r[1] * w0.y + r[2] * w0.z + r[3] * w0.w +
              r[4] * w1.x + r[5] * w1.y + r[6] * w1.z + r[7] * w1.w;
#pragma unroll
    for (int off = 8; off > 0; off >>= 1) p += __shfl_down(p, off, 16);
    if (sl == 0) out[node] = p + bl[0];
}

// ---------------- launch ----------------
extern "C" void kernel_launch(void* const* d_in, const int* in_sizes, int n_in,
                              void* d_out, int out_size, void* d_ws, size_t ws_size,
                              hipStream_t stream) {
    const float* x  = (const float*)d_in[0];
    const int*   ei = (const int*)d_in[1];
    const float* W1 = (const float*)d_in[2];
    const float* b1 = (const float*)d_in[3];
    const float* W2 = (const float*)d_in[4];
    const float* b2 = (const float*)d_in[5];
    const float* Wl = (const float*)d_in[6];
    const float* bl = (const float*)d_in[7];
    float* out = (float*)d_out;

    int N = in_sizes[0] / DHID;     // 100000
    int E = in_sizes[1] / 2;        // 1600000
    int nbuck = (N + 511) / 512;    // 196
    int nRB = (N + 63) / 64;        // 1563
    int nPart = (E + PCHUNK - 1) / PCHUNK;  // 391

    char* ws = (char*)d_ws;
    size_t off = 0;
    auto alloc = [&](size_t bytes) -> void* {
        void* p = ws + off;
        off += (bytes + 255) & ~(size_t)255;
        return p;
    };
    float*    dinv     = (float*)alloc((size_t)N * 4);
    int*      row_ptr  = (int*)alloc((size_t)(N + 1) * 4);
    int*      bcur     = (int*)alloc((size_t)nbuck * 4);
    int*      csr      = (int*)alloc((size_t)E * 4);
    unsigned* packed   = (unsigned*)alloc((size_t)nbuck * BCAP * 4);
    _Float16* Th       = (_Float16*)alloc((size_t)N * DHID * 2);
    _Float16* Th2      = (_Float16*)alloc((size_t)N * DHID * 2);
    _Float16* W2t      = (_Float16*)alloc((size_t)DHID * DHID * 2);

    (void)hipMemsetAsync(bcur, 0, (size_t)nbuck * 4, stream);

    // K1: gemm1 || edge partition (independent; fused grid)
    k_front<<<nRB + nPart, 256, 0, stream>>>(x, W1, Th, N, nRB, ei, E, nbuck, bcur, packed);
    // K2: counting sort -> row_ptr/dinv/csr; +1 block: W2 -> W2t fp16 transpose
    k_p2b<<<nbuck + 1, 256, 0, stream>>>(packed, bcur, row_ptr, dinv, csr, W2, W2t, nbuck, N, E);
    // K3: agg layer-1 + fused gemm2 -> Th2
    k_agg_gemm<<<(N + 15) / 16, 256, 0, stream>>>(Th, row_ptr, csr, dinv, b1, W2t, Th2, N);
    // K4: final agg + Wl projection
    k_agg_fin<<<(N + 15) / 16, 256, 0, stream>>>(Th2, row_ptr, csr, dinv, b2, Wl, bl, out, N);
}

// Round 11
// 208.083 us; speedup vs baseline: 2.3336x; 1.0109x over previous
//
#include <hip/hip_runtime.h>

#define DHID 128
#define BCAP 10240         // per-bucket capacity (mean 8163, 23 sigma)
#define PCHUNK 4096        // edges per partition block
#define XS_LD 136          // LDS row stride in fp16 elems (128 + 8 pad)
#define SMEM_BYTES 21504   // union: partition 21504B > gemm 64*136*2=17408B

typedef _Float16 h4 __attribute__((ext_vector_type(4)));
typedef _Float16 h8 __attribute__((ext_vector_type(8)));
typedef float    f32x4 __attribute__((ext_vector_type(4)));

// ---- hoist A-frags = W^T for wave w (cols w*32..+31) from fp16 col-major Wt ----
// a[j] = W[k = kb*32+lq*8+j][c] = Wt[c*128 + k] -> contiguous h8 loads.
__device__ inline void hoist_afrag_f16(const _Float16* __restrict__ Wt, int w, int l16, int lq,
                                       h8 afrag[2][4]) {
#pragma unroll
    for (int ct = 0; ct < 2; ++ct) {
        int c = w * 32 + ct * 16 + l16;
#pragma unroll
        for (int kb = 0; kb < 4; ++kb)
            afrag[ct][kb] = *(const h8*)(Wt + (size_t)c * DHID + kb * 32 + lq * 8);
    }
}

// ---- k_prep: block 0: W1 -> W1t fp16 col-major; block 1: W2 -> W2t ----
__global__ __launch_bounds__(256) void k_prep(const float* __restrict__ W1,
                                              const float* __restrict__ W2,
                                              _Float16* __restrict__ W1t,
                                              _Float16* __restrict__ W2t) {
    const float* W = (blockIdx.x == 0) ? W1 : W2;
    _Float16* Wt   = (blockIdx.x == 0) ? W1t : W2t;
    int t = threadIdx.x;
    int c = t & 127, k0 = (t >> 7) * 64;
#pragma unroll
    for (int kb = 0; kb < 8; ++kb) {
        h8 v;
#pragma unroll
        for (int j = 0; j < 8; ++j)
            v[j] = (_Float16)W[(size_t)(k0 + kb * 8 + j) * DHID + c];
        *(h8*)(Wt + (size_t)c * DHID + k0 + kb * 8) = v;
    }
}

// ---- gemm1 body: Th[N,128] = fp16(X @ W1), UNSCALED (dinv applied in agg) ----
// A := W1^T hoisted from fp16 W1t, B := X^T from LDS tile (staged once per block).
__device__ inline void gemm1_body(char* smem, const float* __restrict__ X,
                                  const _Float16* __restrict__ W1t,
                                  _Float16* __restrict__ Th, int N, int blk) {
    _Float16* Xs = (_Float16*)smem;
    int t = threadIdx.x;
    int w = t >> 6, l = t & 63, l16 = l & 15, lq = l >> 4;

    h8 afrag[2][4];
    hoist_afrag_f16(W1t, w, l16, lq, afrag);

    int rs = t >> 2, cs = (t & 3) * 32;
    int r0 = blk * 64;
    {
        int rg = r0 + rs; if (rg > N - 1) rg = N - 1;
        _Float16* sp = Xs + rs * XS_LD + cs;
        const float* xp = X + (size_t)rg * DHID + cs;
#pragma unroll
        for (int k = 0; k < 4; ++k) {
            float4 a = *(const float4*)(xp + k * 8);
            float4 b = *(const float4*)(xp + k * 8 + 4);
            h8 v;
            v[0] = (_Float16)a.x; v[1] = (_Float16)a.y;
            v[2] = (_Float16)a.z; v[3] = (_Float16)a.w;
            v[4] = (_Float16)b.x; v[5] = (_Float16)b.y;
            v[6] = (_Float16)b.z; v[7] = (_Float16)b.w;
            *(h8*)(sp + k * 8) = v;
        }
    }
    __syncthreads();

    f32x4 acc[4][2];
#pragma unroll
    for (int rt = 0; rt < 4; ++rt)
#pragma unroll
        for (int ct = 0; ct < 2; ++ct) acc[rt][ct] = (f32x4){0.f, 0.f, 0.f, 0.f};

#pragma unroll
    for (int rt = 0; rt < 4; ++rt) {
        const _Float16* bp = Xs + (rt * 16 + l16) * XS_LD + lq * 8;
#pragma unroll
        for (int kb = 0; kb < 4; ++kb) {
            h8 b = *(const h8*)(bp + kb * 32);
            acc[rt][0] = __builtin_amdgcn_mfma_f32_16x16x32_f16(afrag[0][kb], b, acc[rt][0], 0, 0, 0);
            acc[rt][1] = __builtin_amdgcn_mfma_f32_16x16x32_f16(afrag[1][kb], b, acc[rt][1], 0, 0, 0);
        }
    }

#pragma unroll
    for (int rt = 0; rt < 4; ++rt) {
        int r = r0 + rt * 16 + l16;
        if (r < N) {
#pragma unroll
            for (int ct = 0; ct < 2; ++ct) {
                h4 v;
#pragma unroll
                for (int j = 0; j < 4; ++j) v[j] = (_Float16)acc[rt][ct][j];
                *(h4*)(Th + (size_t)r * DHID + w * 32 + ct * 16 + lq * 4) = v;
            }
        }
    }
}

// ---- partition body: bucket edges by dst>>9; packed entry (dst&511)<<17 | src ----
__device__ inline void partition_body(char* smem, const int* __restrict__ ei, int E, int nbuck,
                                      int* __restrict__ bcur, unsigned* __restrict__ packed, int blk) {
    unsigned* sdata = (unsigned*)smem;          // 16384 B
    int* lcnt  = (int*)(smem + 16384);
    int* lbase = (int*)(smem + 17408);
    int* loff  = (int*)(smem + 18432);
    int* lcur  = (int*)(smem + 19456);
    int* sscan = (int*)(smem + 20480);
    int t = threadIdx.x;
    int e0 = blk * PCHUNK;
    lcnt[t] = 0;
    __syncthreads();

    int sreg[16], dreg[16];
#pragma unroll
    for (int k = 0; k < 16; ++k) {
        int e = e0 + t + k * 256;
        if (e < E) { sreg[k] = ei[e]; dreg[k] = ei[E + e]; }
        else dreg[k] = -1;
    }

#pragma unroll
    for (int k = 0; k < 16; ++k)
        if (dreg[k] >= 0) atomicAdd(&lcnt[dreg[k] >> 9], 1);
    __syncthreads();

    int c = lcnt[t];
    sscan[t] = c;
    __syncthreads();
    for (int off = 1; off < 256; off <<= 1) {
        int v = (t >= off) ? sscan[t - off] : 0;
        __syncthreads();
        sscan[t] += v;
        __syncthreads();
    }
    loff[t] = sscan[t] - c;
    if (t < nbuck && c > 0) lbase[t] = atomicAdd(&bcur[t], c);
    lcur[t] = sscan[t] - c;
    __syncthreads();

#pragma unroll
    for (int k = 0; k < 16; ++k) {
        if (dreg[k] >= 0) {
            int b = dreg[k] >> 9;
            int pos = atomicAdd(&lcur[b], 1);
            sdata[pos] = ((unsigned)(dreg[k] & 511) << 17) | (unsigned)sreg[k];
        }
    }
    __syncthreads();

    int wid = t >> 6, lane = t & 63;
    for (int b = wid; b < nbuck; b += 4) {
        int cb = lcnt[b];
        if (cb == 0) continue;
        int gbase = b * BCAP + lbase[b];
        int sbase = loff[b];
        for (int k = lane; k < cb; k += 64) packed[gbase + k] = sdata[sbase + k];
    }
}

// ---- K1: gemm1 (blocks < nRB) || edge partition (blocks >= nRB) — independent work ----
__global__ __launch_bounds__(256) void k_front(const float* __restrict__ X,
                                               const _Float16* __restrict__ W1t,
                                               _Float16* __restrict__ Th, int N, int nRB,
                                               const int* __restrict__ ei, int E, int nbuck,
                                               int* __restrict__ bcur, unsigned* __restrict__ packed) {
    __shared__ __align__(16) char smem[SMEM_BYTES];
    if ((int)blockIdx.x < nRB)
        gemm1_body(smem, X, W1t, Th, N, blockIdx.x);
    else
        partition_body(smem, ei, E, nbuck, bcur, packed, blockIdx.x - nRB);
}

// ---- K2: per-bucket counting sort -> row_ptr, dinv, csr (self-scans bucket totals) ----
__global__ __launch_bounds__(256) void k_p2b(const unsigned* __restrict__ packed,
                                             const int* __restrict__ bcur,
                                             int* __restrict__ row_ptr,
                                             float* __restrict__ dinv,
                                             int* __restrict__ csr,
                                             int nbuck, int N, int E) {
    __shared__ int c512[512], cur512[512], sscan[256], sbk[256];
    int t = threadIdx.x, b = blockIdx.x;
    sbk[t] = (t < nbuck) ? bcur[t] : 0;
    c512[t] = 0; c512[t + 256] = 0;
    __syncthreads();
    for (int off = 1; off < 256; off <<= 1) {   // inclusive scan of bucket totals
        int v = (t >= off) ? sbk[t - off] : 0;
        __syncthreads();
        sbk[t] += v;
        __syncthreads();
    }
    int rbase = (b > 0) ? sbk[b - 1] : 0;
    int m = bcur[b];
    const unsigned* pb = packed + (size_t)b * BCAP;
    for (int i = t; i < m; i += 256) atomicAdd(&c512[pb[i] >> 17], 1);
    __syncthreads();
    int v0 = c512[2 * t], v1 = c512[2 * t + 1];
    int ps = v0 + v1;
    sscan[t] = ps;
    __syncthreads();
    for (int off = 1; off < 256; off <<= 1) {
        int v = (t >= off) ? sscan[t - off] : 0;
        __syncthreads();
        sscan[t] += v;
        __syncthreads();
    }
    int excl = sscan[t] - ps;
    cur512[2 * t] = excl;
    cur512[2 * t + 1] = excl + v0;

    int n0 = (b << 9) + 2 * t;
    if (n0 < N) {
        row_ptr[n0] = rbase + excl;
        dinv[n0] = rsqrtf((float)(v0 + 1));     // +1 self-loop
    }
    if (n0 + 1 < N) {
        row_ptr[n0 + 1] = rbase + excl + v0;
        dinv[n0 + 1] = rsqrtf((float)(v1 + 1));
    }
    if (b == 0 && t == 0) row_ptr[N] = E;
    __syncthreads();

    for (int i = t; i < m; i += 256) {
        unsigned p = pb[i];
        int dl = p >> 17;
        int src = (int)(p & 0x1FFFFu);
        int pos = atomicAdd(&cur512[dl], 1);
        csr[rbase + pos] = src;
    }
}

// ---- K3a: agg layer-1 -> H fp16.  Pure gather, NO barrier (R10 lesson: never
// barrier-couple a latency-bound gather).  16 nodes/block, 16 lanes x h8/node. ----
__global__ __launch_bounds__(256) void k_agg_mid(const _Float16* __restrict__ Th,
                                                 const int* __restrict__ row_ptr,
                                                 const int* __restrict__ csr,
                                                 const float* __restrict__ dinv,
                                                 const float* __restrict__ bias,
                                                 _Float16* __restrict__ H, int N) {
    int node = blockIdx.x * 16 + (threadIdx.x >> 4);
    int sl = threadIdx.x & 15;
    if (node >= N) return;

    int e = row_ptr[node];
    int end = row_ptr[node + 1];
    const h8* Tl = (const h8*)Th + sl;

    float acc[8];
#pragma unroll
    for (int c = 0; c < 8; ++c) acc[c] = 0.f;

    for (; e + 4 <= end; e += 4) {
        int s0 = csr[e], s1 = csr[e + 1], s2 = csr[e + 2], s3 = csr[e + 3];
        float d0 = dinv[s0], d1 = dinv[s1], d2 = dinv[s2], d3 = dinv[s3];
        h8 v0 = Tl[(size_t)s0 * 16];
        h8 v1 = Tl[(size_t)s1 * 16];
        h8 v2 = Tl[(size_t)s2 * 16];
        h8 v3 = Tl[(size_t)s3 * 16];
#pragma unroll
        for (int c = 0; c < 8; ++c) {
            float a0 = fmaf(d0, (float)v0[c], fmaf(d1, (float)v1[c], 0.f));
            float a1 = fmaf(d2, (float)v2[c], fmaf(d3, (float)v3[c], 0.f));
            acc[c] += a0 + a1;
        }
    }
    for (; e < end; ++e) {
        int s0 = csr[e];
        float d0 = dinv[s0];
        h8 va = Tl[(size_t)s0 * 16];
#pragma unroll
        for (int c = 0; c < 8; ++c) acc[c] = fmaf(d0, (float)va[c], acc[c]);
    }

    float dn = dinv[node];
    {   // self-loop
        h8 tv = Tl[(size_t)node * 16];
#pragma unroll
        for (int c = 0; c < 8; ++c) acc[c] = fmaf(dn, (float)tv[c], acc[c]);
    }

    const float* bp = bias + sl * 8;
    float4 b0 = *(const float4*)bp;
    float4 b1 = *(const float4*)(bp + 4);
    h8 hv;
    hv[0] = (_Float16)fmaxf(fmaf(dn, acc[0], b0.x), 0.f);
    hv[1] = (_Float16)fmaxf(fmaf(dn, acc[1], b0.y), 0.f);
    hv[2] = (_Float16)fmaxf(fmaf(dn, acc[2], b0.z), 0.f);
    hv[3] = (_Float16)fmaxf(fmaf(dn, acc[3], b0.w), 0.f);
    hv[4] = (_Float16)fmaxf(fmaf(dn, acc[4], b1.x), 0.f);
    hv[5] = (_Float16)fmaxf(fmaf(dn, acc[5], b1.y), 0.f);
    hv[6] = (_Float16)fmaxf(fmaf(dn, acc[6], b1.z), 0.f);
    hv[7] = (_Float16)fmaxf(fmaf(dn, acc[7], b1.w), 0.f);
    *(h8*)(H + (size_t)node * DHID + sl * 8) = hv;
}

// ---- K3b: gemm2: Th2[N,128] = fp16(H @ W2), unscaled.  fp16 in, LDS-staged. ----
__global__ __launch_bounds__(256) void k_gemm_l2(const _Float16* __restrict__ H,
                                                 const _Float16* __restrict__ W2t,
                                                 _Float16* __restrict__ Th2, int N) {
    __shared__ _Float16 Xs[64 * XS_LD];
    int t = threadIdx.x;
    int w = t >> 6, l = t & 63, l16 = l & 15, lq = l >> 4;

    h8 afrag[2][4];
    hoist_afrag_f16(W2t, w, l16, lq, afrag);

    int rs = t >> 2, cs = (t & 3) * 32;
    int r0 = blockIdx.x * 64;
    {
        int rg = r0 + rs; if (rg > N - 1) rg = N - 1;
        _Float16* sp = Xs + rs * XS_LD + cs;
        const _Float16* xp = H + (size_t)rg * DHID + cs;
#pragma unroll
        for (int k = 0; k < 4; ++k)
            *(h8*)(sp + k * 8) = *(const h8*)(xp + k * 8);
    }
    __syncthreads();

    f32x4 acc[4][2];
#pragma unroll
    for (int rt = 0; rt < 4; ++rt)
#pragma unroll
        for (int ct = 0; ct < 2; ++ct) acc[rt][ct] = (f32x4){0.f, 0.f, 0.f, 0.f};

#pragma unroll
    for (int rt = 0; rt < 4; ++rt) {
        const _Float16* bp = Xs + (rt * 16 + l16) * XS_LD + lq * 8;
#pragma unroll
        for (int kb = 0; kb < 4; ++kb) {
            h8 b = *(const h8*)(bp + kb * 32);
            acc[rt][0] = __builtin_amdgcn_mfma_f32_16x16x32_f16(afrag[0][kb], b, acc[rt][0], 0, 0, 0);
            acc[rt][1] = __builtin_amdgcn_mfma_f32_16x16x32_f16(afrag[1][kb], b, acc[rt][1], 0, 0, 0);
        }
    }

#pragma unroll
    for (int rt = 0; rt < 4; ++rt) {
        int r = r0 + rt * 16 + l16;
        if (r < N) {
#pragma unroll
            for (int ct = 0; ct < 2; ++ct) {
                h4 v;
#pragma unroll
                for (int j = 0; j < 4; ++j) v[j] = (_Float16)acc[rt][ct][j];
                *(h4*)(Th2 + (size_t)r * DHID + w * 32 + ct * 16 + lq * 4) = v;
            }
        }
    }
}

// ---- K4: final agg + Wl projection.  Th2 unscaled -> per-edge dinv weights. ----
__global__ __launch_bounds__(256) void k_agg_fin(const _Float16* __restrict__ Th2,
                                                 const int* __restrict__ row_ptr,
                                                 const int* __restrict__ csr,
                                                 const float* __restrict__ dinv,
                                                 const float* __restrict__ bias,
                                                 const float* __restrict__ Wl,
                                                 const float* __restrict__ bl,
                                                 float* __restrict__ out, int N) {
    int node = blockIdx.x * 16 + (threadIdx.x >> 4);
    int sl = threadIdx.x & 15;
    if (node >= N) return;

    int e = row_ptr[node];
    int end = row_ptr[node + 1];
    const h8* Tl = (const h8*)Th2 + sl;

    float acc[8];
#pragma unroll
    for (int c = 0; c < 8; ++c) acc[c] = 0.f;

    for (; e + 4 <= end; e += 4) {
        int s0 = csr[e], s1 = csr[e + 1], s2 = csr[e + 2], s3 = csr[e + 3];
        float d0 = dinv[s0], d1 = dinv[s1], d2 = dinv[s2], d3 = dinv[s3];
        h8 v0 = Tl[(size_t)s0 * 16];
        h8 v1 = Tl[(size_t)s1 * 16];
        h8 v2 = Tl[(size_t)s2 * 16];
        h8 v3 = Tl[(size_t)s3 * 16];
#pragma unroll
        for (int c = 0; c < 8; ++c) {
            float a0 = fmaf(d0, (float)v0[c], fmaf(d1, (float)v1[c], 0.f));
            float a1 = fmaf(d2, (float)v2[c], fmaf(d3, (float)v3[c], 0.f));
            acc[c] += a0 + a1;
        }
    }
    for (; e < end; ++e) {
        int s0 = csr[e];
        float d0 = dinv[s0];
        h8 va = Tl[(size_t)s0 * 16];
#pragma unroll
        for (int c = 0; c < 8; ++c) acc[c] = fmaf(d0, (float)va[c], acc[c]);
    }

    float dn = dinv[node];
    {   // self-loop
        h8 tv = Tl[(size_t)node * 16];
#pragma unroll
        for (int c = 0; c < 8; ++c) acc[c] = fmaf(dn, (float)tv[c], acc[c]);
    }

    const float* bp = bias + sl * 8;
    float4 b0 = *(const float4*)bp;
    float4 b1 = *(const float4*)(bp + 4);
    float r[8];
    r[0] = fmaxf(fmaf(dn, acc[0], b0.x), 0.f);
    r[1] = fmaxf(fmaf(dn, acc[1], b0.y), 0.f);
    r[2] = fmaxf(fmaf(dn, acc[2], b0.z), 0.f);
    r[3] = fmaxf(fmaf(dn, acc[3], b0.w), 0.f);
    r[4] = fmaxf(fmaf(dn, acc[4], b1.x), 0.f);
    r[5] = fmaxf(fmaf(dn, acc[5], b1.y), 0.f);
    r[6] = fmaxf(fmaf(dn, acc[6], b1.z), 0.f);
    r[7] = fmaxf(fmaf(dn, acc[7], b1.w), 0.f);

    const float* wp = Wl + sl * 8;
    float4 w0 = *(const float4*)wp;
    float4 w1 = *(const float4*)(wp + 4);
    float p = r[0] * w0.x + r[1] * w0.y + r[2] * w0.z + r[3] * w0.w +
              r[4] * w1.x + r[5] * w1.y + r[6] * w1.z + r[7] * w1.w;
#pragma unroll
    for (int off = 8; off > 0; off >>= 1) p += __shfl_down(p, off, 16);
    if (sl == 0) out[node] = p + bl[0];
}

// ---------------- launch ----------------
extern "C" void kernel_launch(void* const* d_in, const int* in_sizes, int n_in,
                              void* d_out, int out_size, void* d_ws, size_t ws_size,
                              hipStream_t stream) {
    const float* x  = (const float*)d_in[0];
    const int*   ei = (const int*)d_in[1];
    const float* W1 = (const float*)d_in[2];
    const float* b1 = (const float*)d_in[3];
    const float* W2 = (const float*)d_in[4];
    const float* b2 = (const float*)d_in[5];
    const float* Wl = (const float*)d_in[6];
    const float* bl = (const float*)d_in[7];
    float* out = (float*)d_out;

    int N = in_sizes[0] / DHID;     // 100000
    int E = in_sizes[1] / 2;        // 1600000
    int nbuck = (N + 511) / 512;    // 196
    int nRB = (N + 63) / 64;        // 1563
    int nPart = (E + PCHUNK - 1) / PCHUNK;  // 391

    char* ws = (char*)d_ws;
    size_t off = 0;
    auto alloc = [&](size_t bytes) -> void* {
        void* p = ws + off;
        off += (bytes + 255) & ~(size_t)255;
        return p;
    };
    float*    dinv     = (float*)alloc((size_t)N * 4);
    int*      row_ptr  = (int*)alloc((size_t)(N + 1) * 4);
    int*      bcur     = (int*)alloc((size_t)nbuck * 4);
    int*      csr      = (int*)alloc((size_t)E * 4);
    unsigned* packed   = (unsigned*)alloc((size_t)nbuck * BCAP * 4);
    _Float16* Th       = (_Float16*)alloc((size_t)N * DHID * 2);
    _Float16* Th2      = (_Float16*)alloc((size_t)N * DHID * 2);  // also reused as H
    _Float16* H        = (_Float16*)alloc((size_t)N * DHID * 2);
    _Float16* W1t      = (_Float16*)alloc((size_t)DHID * DHID * 2);
    _Float16* W2t      = (_Float16*)alloc((size_t)DHID * DHID * 2);

    (void)hipMemsetAsync(bcur, 0, (size_t)nbuck * 4, stream);

    // K0: weight transposes to fp16 col-major (same RNE rounding as before)
    k_prep<<<2, 256, 0, stream>>>(W1, W2, W1t, W2t);
    // K1: gemm1 || edge partition (independent; fused grid)
    k_front<<<nRB + nPart, 256, 0, stream>>>(x, W1t, Th, N, nRB, ei, E, nbuck, bcur, packed);
    // K2: counting sort -> row_ptr/dinv/csr
    k_p2b<<<nbuck, 256, 0, stream>>>(packed, bcur, row_ptr, dinv, csr, nbuck, N, E);
    // K3a: agg layer-1 -> H (pure gather, no barrier)
    k_agg_mid<<<(N + 15) / 16, 256, 0, stream>>>(Th, row_ptr, csr, dinv, b1, H, N);
    // K3b: gemm2 -> Th2
    k_gemm_l2<<<nRB, 256, 0, stream>>>(H, W2t, Th2, N);
    // K4: final agg + Wl projection
    k_agg_fin<<<(N + 15) / 16, 256, 0, stream>>>(Th2, row_ptr, csr, dinv, b2, Wl, bl, out, N);
}

// Round 12
// 200.958 us; speedup vs baseline: 2.4163x; 1.0355x over previous
//
#include <hip/hip_runtime.h>

#define DHID 128
#define BCAP 10240         // per-bucket capacity (mean 8163, 23 sigma)
#define PCHUNK 4096        // edges per partition block
#define XS_LD 136          // LDS row stride in fp16 elems (128 + 8 pad)
#define SMEM_PART 21504    // partition smem bytes
#define SMEM_MID  17408    // gemm1 tile 64*136*2 (> p2b's 6144)

typedef _Float16 h4 __attribute__((ext_vector_type(4)));
typedef _Float16 h8 __attribute__((ext_vector_type(8)));
typedef float    f32x4 __attribute__((ext_vector_type(4)));

// ---- hoist A-frags = W^T for wave w (cols w*32..+31) from fp16 col-major Wt ----
__device__ inline void hoist_afrag_f16(const _Float16* __restrict__ Wt, int w, int l16, int lq,
                                       h8 afrag[2][4]) {
#pragma unroll
    for (int ct = 0; ct < 2; ++ct) {
        int c = w * 32 + ct * 16 + l16;
#pragma unroll
        for (int kb = 0; kb < 4; ++kb)
            afrag[ct][kb] = *(const h8*)(Wt + (size_t)c * DHID + kb * 32 + lq * 8);
    }
}

// ---- transpose body: Wt[c][k] = fp16(W[k][c]) (256 threads, 1 block) ----
__device__ inline void wtrans_body(const float* __restrict__ W, _Float16* __restrict__ Wt) {
    int t = threadIdx.x;
    int c = t & 127, k0 = (t >> 7) * 64;
#pragma unroll
    for (int kb = 0; kb < 8; ++kb) {
        h8 v;
#pragma unroll
        for (int j = 0; j < 8; ++j)
            v[j] = (_Float16)W[(size_t)(k0 + kb * 8 + j) * DHID + c];
        *(h8*)(Wt + (size_t)c * DHID + k0 + kb * 8) = v;
    }
}

// ---- partition body: bucket edges by dst>>9; packed entry (dst&511)<<17 | src ----
__device__ inline void partition_body(char* smem, const int* __restrict__ ei, int E, int nbuck,
                                      int* __restrict__ bcur, unsigned* __restrict__ packed, int blk) {
    unsigned* sdata = (unsigned*)smem;          // 16384 B
    int* lcnt  = (int*)(smem + 16384);
    int* lbase = (int*)(smem + 17408);
    int* loff  = (int*)(smem + 18432);
    int* lcur  = (int*)(smem + 19456);
    int* sscan = (int*)(smem + 20480);
    int t = threadIdx.x;
    int e0 = blk * PCHUNK;
    lcnt[t] = 0;
    __syncthreads();

    int sreg[16], dreg[16];
#pragma unroll
    for (int k = 0; k < 16; ++k) {
        int e = e0 + t + k * 256;
        if (e < E) { sreg[k] = ei[e]; dreg[k] = ei[E + e]; }
        else dreg[k] = -1;
    }

#pragma unroll
    for (int k = 0; k < 16; ++k)
        if (dreg[k] >= 0) atomicAdd(&lcnt[dreg[k] >> 9], 1);
    __syncthreads();

    int c = lcnt[t];
    sscan[t] = c;
    __syncthreads();
    for (int off = 1; off < 256; off <<= 1) {
        int v = (t >= off) ? sscan[t - off] : 0;
        __syncthreads();
        sscan[t] += v;
        __syncthreads();
    }
    loff[t] = sscan[t] - c;
    if (t < nbuck && c > 0) lbase[t] = atomicAdd(&bcur[t], c);
    lcur[t] = sscan[t] - c;
    __syncthreads();

#pragma unroll
    for (int k = 0; k < 16; ++k) {
        if (dreg[k] >= 0) {
            int b = dreg[k] >> 9;
            int pos = atomicAdd(&lcur[b], 1);
            sdata[pos] = ((unsigned)(dreg[k] & 511) << 17) | (unsigned)sreg[k];
        }
    }
    __syncthreads();

    int wid = t >> 6, lane = t & 63;
    for (int b = wid; b < nbuck; b += 4) {
        int cb = lcnt[b];
        if (cb == 0) continue;
        int gbase = b * BCAP + lbase[b];
        int sbase = loff[b];
        for (int k = lane; k < cb; k += 64) packed[gbase + k] = sdata[sbase + k];
    }
}

// ---- K0: edge partition (blocks < nPart) ∥ W1/W2 fp16 transposes (2 tail blocks) ----
__global__ __launch_bounds__(256) void k_part(const int* __restrict__ ei, int E, int nbuck,
                                              int* __restrict__ bcur, unsigned* __restrict__ packed,
                                              const float* __restrict__ W1, const float* __restrict__ W2,
                                              _Float16* __restrict__ W1t, _Float16* __restrict__ W2t,
                                              int nPart) {
    __shared__ __align__(16) char smem[SMEM_PART];
    int b = blockIdx.x;
    if (b < nPart)            partition_body(smem, ei, E, nbuck, bcur, packed, b);
    else if (b == nPart)      wtrans_body(W1, W1t);
    else                      wtrans_body(W2, W2t);
}

// ---- p2b body: per-bucket counting sort -> row_ptr, dinv, csr ----
__device__ inline void p2b_body(char* smem, const unsigned* __restrict__ packed,
                                const int* __restrict__ bcur,
                                int* __restrict__ row_ptr, float* __restrict__ dinv,
                                int* __restrict__ csr, int nbuck, int N, int E, int b) {
    int* c512   = (int*)smem;             // 2048 B
    int* cur512 = (int*)(smem + 2048);    // 2048 B
    int* sscan  = (int*)(smem + 4096);    // 1024 B
    int* sbk    = (int*)(smem + 5120);    // 1024 B
    int t = threadIdx.x;
    sbk[t] = (t < nbuck) ? bcur[t] : 0;
    c512[t] = 0; c512[t + 256] = 0;
    __syncthreads();
    for (int off = 1; off < 256; off <<= 1) {   // inclusive scan of bucket totals
        int v = (t >= off) ? sbk[t - off] : 0;
        __syncthreads();
        sbk[t] += v;
        __syncthreads();
    }
    int rbase = (b > 0) ? sbk[b - 1] : 0;
    int m = bcur[b];
    const unsigned* pb = packed + (size_t)b * BCAP;
    for (int i = t; i < m; i += 256) atomicAdd(&c512[pb[i] >> 17], 1);
    __syncthreads();
    int v0 = c512[2 * t], v1 = c512[2 * t + 1];
    int ps = v0 + v1;
    sscan[t] = ps;
    __syncthreads();
    for (int off = 1; off < 256; off <<= 1) {
        int v = (t >= off) ? sscan[t - off] : 0;
        __syncthreads();
        sscan[t] += v;
        __syncthreads();
    }
    int excl = sscan[t] - ps;
    cur512[2 * t] = excl;
    cur512[2 * t + 1] = excl + v0;

    int n0 = (b << 9) + 2 * t;
    if (n0 < N) {
        row_ptr[n0] = rbase + excl;
        dinv[n0] = rsqrtf((float)(v0 + 1));     // +1 self-loop
    }
    if (n0 + 1 < N) {
        row_ptr[n0 + 1] = rbase + excl + v0;
        dinv[n0 + 1] = rsqrtf((float)(v1 + 1));
    }
    if (b == 0 && t == 0) row_ptr[N] = E;
    __syncthreads();

    for (int i = t; i < m; i += 256) {
        unsigned p = pb[i];
        int dl = p >> 17;
        int src = (int)(p & 0x1FFFFu);
        int pos = atomicAdd(&cur512[dl], 1);
        csr[rbase + pos] = src;
    }
}

// ---- gemm1 body: Th[N,128] = fp16(X @ W1), UNSCALED (dinv applied in agg) ----
__device__ inline void gemm1_body(char* smem, const float* __restrict__ X,
                                  const _Float16* __restrict__ W1t,
                                  _Float16* __restrict__ Th, int N, int blk) {
    _Float16* Xs = (_Float16*)smem;
    int t = threadIdx.x;
    int w = t >> 6, l = t & 63, l16 = l & 15, lq = l >> 4;

    h8 afrag[2][4];
    hoist_afrag_f16(W1t, w, l16, lq, afrag);

    int rs = t >> 2, cs = (t & 3) * 32;
    int r0 = blk * 64;
    {
        int rg = r0 + rs; if (rg > N - 1) rg = N - 1;
        _Float16* sp = Xs + rs * XS_LD + cs;
        const float* xp = X + (size_t)rg * DHID + cs;
#pragma unroll
        for (int k = 0; k < 4; ++k) {
            float4 a = *(const float4*)(xp + k * 8);
            float4 b = *(const float4*)(xp + k * 8 + 4);
            h8 v;
            v[0] = (_Float16)a.x; v[1] = (_Float16)a.y;
            v[2] = (_Float16)a.z; v[3] = (_Float16)a.w;
            v[4] = (_Float16)b.x; v[5] = (_Float16)b.y;
            v[6] = (_Float16)b.z; v[7] = (_Float16)b.w;
            *(h8*)(sp + k * 8) = v;
        }
    }
    __syncthreads();

    f32x4 acc[4][2];
#pragma unroll
    for (int rt = 0; rt < 4; ++rt)
#pragma unroll
        for (int ct = 0; ct < 2; ++ct) acc[rt][ct] = (f32x4){0.f, 0.f, 0.f, 0.f};

#pragma unroll
    for (int rt = 0; rt < 4; ++rt) {
        const _Float16* bp = Xs + (rt * 16 + l16) * XS_LD + lq * 8;
#pragma unroll
        for (int kb = 0; kb < 4; ++kb) {
            h8 b = *(const h8*)(bp + kb * 32);
            acc[rt][0] = __builtin_amdgcn_mfma_f32_16x16x32_f16(afrag[0][kb], b, acc[rt][0], 0, 0, 0);
            acc[rt][1] = __builtin_amdgcn_mfma_f32_16x16x32_f16(afrag[1][kb], b, acc[rt][1], 0, 0, 0);
        }
    }

#pragma unroll
    for (int rt = 0; rt < 4; ++rt) {
        int r = r0 + rt * 16 + l16;
        if (r < N) {
#pragma unroll
            for (int ct = 0; ct < 2; ++ct) {
                h4 v;
#pragma unroll
                for (int j = 0; j < 4; ++j) v[j] = (_Float16)acc[rt][ct][j];
                *(h4*)(Th + (size_t)r * DHID + w * 32 + ct * 16 + lq * 4) = v;
            }
        }
    }
}

// ---- K1: p2b (blocks < nbuck, dispatched first) ∥ gemm1 (rest) — independent ----
__global__ __launch_bounds__(256) void k_mid(const unsigned* __restrict__ packed,
                                             const int* __restrict__ bcur,
                                             int* __restrict__ row_ptr, float* __restrict__ dinv,
                                             int* __restrict__ csr, int nbuck, int N, int E,
                                             const float* __restrict__ X,
                                             const _Float16* __restrict__ W1t,
                                             _Float16* __restrict__ Th) {
    __shared__ __align__(16) char smem[SMEM_MID];
    int b = blockIdx.x;
    if (b < nbuck)
        p2b_body(smem, packed, bcur, row_ptr, dinv, csr, nbuck, N, E, b);
    else
        gemm1_body(smem, X, W1t, Th, N, b - nbuck);
}

// ---- K2: agg layer-1 -> H fp16.  Pure gather, NO barrier (R10 lesson). ----
__global__ __launch_bounds__(256) void k_agg_mid(const _Float16* __restrict__ Th,
                                                 const int* __restrict__ row_ptr,
                                                 const int* __restrict__ csr,
                                                 const float* __restrict__ dinv,
                                                 const float* __restrict__ bias,
                                                 _Float16* __restrict__ H, int N) {
    int node = blockIdx.x * 16 + (threadIdx.x >> 4);
    int sl = threadIdx.x & 15;
    if (node >= N) return;

    int e = row_ptr[node];
    int end = row_ptr[node + 1];
    const h8* Tl = (const h8*)Th + sl;

    float acc[8];
#pragma unroll
    for (int c = 0; c < 8; ++c) acc[c] = 0.f;

    for (; e + 4 <= end; e += 4) {
        int s0 = csr[e], s1 = csr[e + 1], s2 = csr[e + 2], s3 = csr[e + 3];
        float d0 = dinv[s0], d1 = dinv[s1], d2 = dinv[s2], d3 = dinv[s3];
        h8 v0 = Tl[(size_t)s0 * 16];
        h8 v1 = Tl[(size_t)s1 * 16];
        h8 v2 = Tl[(size_t)s2 * 16];
        h8 v3 = Tl[(size_t)s3 * 16];
#pragma unroll
        for (int c = 0; c < 8; ++c) {
            float a0 = fmaf(d0, (float)v0[c], fmaf(d1, (float)v1[c], 0.f));
            float a1 = fmaf(d2, (float)v2[c], fmaf(d3, (float)v3[c], 0.f));
            acc[c] += a0 + a1;
        }
    }
    for (; e < end; ++e) {
        int s0 = csr[e];
        float d0 = dinv[s0];
        h8 va = Tl[(size_t)s0 * 16];
#pragma unroll
        for (int c = 0; c < 8; ++c) acc[c] = fmaf(d0, (float)va[c], acc[c]);
    }

    float dn = dinv[node];
    {   // self-loop
        h8 tv = Tl[(size_t)node * 16];
#pragma unroll
        for (int c = 0; c < 8; ++c) acc[c] = fmaf(dn, (float)tv[c], acc[c]);
    }

    const float* bp = bias + sl * 8;
    float4 b0 = *(const float4*)bp;
    float4 b1 = *(const float4*)(bp + 4);
    h8 hv;
    hv[0] = (_Float16)fmaxf(fmaf(dn, acc[0], b0.x), 0.f);
    hv[1] = (_Float16)fmaxf(fmaf(dn, acc[1], b0.y), 0.f);
    hv[2] = (_Float16)fmaxf(fmaf(dn, acc[2], b0.z), 0.f);
    hv[3] = (_Float16)fmaxf(fmaf(dn, acc[3], b0.w), 0.f);
    hv[4] = (_Float16)fmaxf(fmaf(dn, acc[4], b1.x), 0.f);
    hv[5] = (_Float16)fmaxf(fmaf(dn, acc[5], b1.y), 0.f);
    hv[6] = (_Float16)fmaxf(fmaf(dn, acc[6], b1.z), 0.f);
    hv[7] = (_Float16)fmaxf(fmaf(dn, acc[7], b1.w), 0.f);
    *(h8*)(H + (size_t)node * DHID + sl * 8) = hv;
}

// ---- K3: gemm2: Th2[N,128] = fp16(H @ W2), unscaled.  fp16 in, LDS-staged. ----
__global__ __launch_bounds__(256) void k_gemm_l2(const _Float16* __restrict__ H,
                                                 const _Float16* __restrict__ W2t,
                                                 _Float16* __restrict__ Th2, int N) {
    __shared__ _Float16 Xs[64 * XS_LD];
    int t = threadIdx.x;
    int w = t >> 6, l = t & 63, l16 = l & 15, lq = l >> 4;

    h8 afrag[2][4];
    hoist_afrag_f16(W2t, w, l16, lq, afrag);

    int rs = t >> 2, cs = (t & 3) * 32;
    int r0 = blockIdx.x * 64;
    {
        int rg = r0 + rs; if (rg > N - 1) rg = N - 1;
        _Float16* sp = Xs + rs * XS_LD + cs;
        const _Float16* xp = H + (size_t)rg * DHID + cs;
#pragma unroll
        for (int k = 0; k < 4; ++k)
            *(h8*)(sp + k * 8) = *(const h8*)(xp + k * 8);
    }
    __syncthreads();

    f32x4 acc[4][2];
#pragma unroll
    for (int rt = 0; rt < 4; ++rt)
#pragma unroll
        for (int ct = 0; ct < 2; ++ct) acc[rt][ct] = (f32x4){0.f, 0.f, 0.f, 0.f};

#pragma unroll
    for (int rt = 0; rt < 4; ++rt) {
        const _Float16* bp = Xs + (rt * 16 + l16) * XS_LD + lq * 8;
#pragma unroll
        for (int kb = 0; kb < 4; ++kb) {
            h8 b = *(const h8*)(bp + kb * 32);
            acc[rt][0] = __builtin_amdgcn_mfma_f32_16x16x32_f16(afrag[0][kb], b, acc[rt][0], 0, 0, 0);
            acc[rt][1] = __builtin_amdgcn_mfma_f32_16x16x32_f16(afrag[1][kb], b, acc[rt][1], 0, 0, 0);
        }
    }

#pragma unroll
    for (int rt = 0; rt < 4; ++rt) {
        int r = r0 + rt * 16 + l16;
        if (r < N) {
#pragma unroll
            for (int ct = 0; ct < 2; ++ct) {
                h4 v;
#pragma unroll
                for (int j = 0; j < 4; ++j) v[j] = (_Float16)acc[rt][ct][j];
                *(h4*)(Th2 + (size_t)r * DHID + w * 32 + ct * 16 + lq * 4) = v;
            }
        }
    }
}

// ---- K4: final agg + Wl projection.  Th2 unscaled -> per-edge dinv weights. ----
__global__ __launch_bounds__(256) void k_agg_fin(const _Float16* __restrict__ Th2,
                                                 const int* __restrict__ row_ptr,
                                                 const int* __restrict__ csr,
                                                 const float* __restrict__ dinv,
                                                 const float* __restrict__ bias,
                                                 const float* __restrict__ Wl,
                                                 const float* __restrict__ bl,
                                                 float* __restrict__ out, int N) {
    int node = blockIdx.x * 16 + (threadIdx.x >> 4);
    int sl = threadIdx.x & 15;
    if (node >= N) return;

    int e = row_ptr[node];
    int end = row_ptr[node + 1];
    const h8* Tl = (const h8*)Th2 + sl;

    float acc[8];
#pragma unroll
    for (int c = 0; c < 8; ++c) acc[c] = 0.f;

    for (; e + 4 <= end; e += 4) {
        int s0 = csr[e], s1 = csr[e + 1], s2 = csr[e + 2], s3 = csr[e + 3];
        float d0 = dinv[s0], d1 = dinv[s1], d2 = dinv[s2], d3 = dinv[s3];
        h8 v0 = Tl[(size_t)s0 * 16];
        h8 v1 = Tl[(size_t)s1 * 16];
        h8 v2 = Tl[(size_t)s2 * 16];
        h8 v3 = Tl[(size_t)s3 * 16];
#pragma unroll
        for (int c = 0; c < 8; ++c) {
            float a0 = fmaf(d0, (float)v0[c], fmaf(d1, (float)v1[c], 0.f));
            float a1 = fmaf(d2, (float)v2[c], fmaf(d3, (float)v3[c], 0.f));
            acc[c] += a0 + a1;
        }
    }
    for (; e < end; ++e) {
        int s0 = csr[e];
        float d0 = dinv[s0];
        h8 va = Tl[(size_t)s0 * 16];
#pragma unroll
        for (int c = 0; c < 8; ++c) acc[c] = fmaf(d0, (float)va[c], acc[c]);
    }

    float dn = dinv[node];
    {   // self-loop
        h8 tv = Tl[(size_t)node * 16];
#pragma unroll
        for (int c = 0; c < 8; ++c) acc[c] = fmaf(dn, (float)tv[c], acc[c]);
    }

    const float* bp = bias + sl * 8;
    float4 b0 = *(const float4*)bp;
    float4 b1 = *(const float4*)(bp + 4);
    float r[8];
    r[0] = fmaxf(fmaf(dn, acc[0], b0.x), 0.f);
    r[1] = fmaxf(fmaf(dn, acc[1], b0.y), 0.f);
    r[2] = fmaxf(fmaf(dn, acc[2], b0.z), 0.f);
    r[3] = fmaxf(fmaf(dn, acc[3], b0.w), 0.f);
    r[4] = fmaxf(fmaf(dn, acc[4], b1.x), 0.f);
    r[5] = fmaxf(fmaf(dn, acc[5], b1.y), 0.f);
    r[6] = fmaxf(fmaf(dn, acc[6], b1.z), 0.f);
    r[7] = fmaxf(fmaf(dn, acc[7], b1.w), 0.f);

    const float* wp = Wl + sl * 8;
    float4 w0 = *(const float4*)wp;
    float4 w1 = *(const float4*)(wp + 4);
    float p = r[0] * w0.x + r[1] * w0.y + r[2] * w0.z + r[3] * w0.w +
              r[4] * w1.x + r[5] * w1.y + r[6] * w1.z + r[7] * w1.w;
#pragma unroll
    for (int off = 8; off > 0; off >>= 1) p += __shfl_down(p, off, 16);
    if (sl == 0) out[node] = p + bl[0];
}

// ---------------- launch ----------------
extern "C" void kernel_launch(void* const* d_in, const int* in_sizes, int n_in,
                              void* d_out, int out_size, void* d_ws, size_t ws_size,
                              hipStream_t stream) {
    const float* x  = (const float*)d_in[0];
    const int*   ei = (const int*)d_in[1];
    const float* W1 = (const float*)d_in[2];
    const float* b1 = (const float*)d_in[3];
    const float* W2 = (const float*)d_in[4];
    const float* b2 = (const float*)d_in[5];
    const float* Wl = (const float*)d_in[6];
    const float* bl = (const float*)d_in[7];
    float* out = (float*)d_out;

    int N = in_sizes[0] / DHID;     // 100000
    int E = in_sizes[1] / 2;        // 1600000
    int nbuck = (N + 511) / 512;    // 196
    int nRB = (N + 63) / 64;        // 1563
    int nPart = (E + PCHUNK - 1) / PCHUNK;  // 391

    char* ws = (char*)d_ws;
    size_t off = 0;
    auto alloc = [&](size_t bytes) -> void* {
        void* p = ws + off;
        off += (bytes + 255) & ~(size_t)255;
        return p;
    };
    float*    dinv     = (float*)alloc((size_t)N * 4);
    int*      row_ptr  = (int*)alloc((size_t)(N + 1) * 4);
    int*      bcur     = (int*)alloc((size_t)nbuck * 4);
    int*      csr      = (int*)alloc((size_t)E * 4);
    unsigned* packed   = (unsigned*)alloc((size_t)nbuck * BCAP * 4);
    _Float16* Th       = (_Float16*)alloc((size_t)N * DHID * 2);
    _Float16* Th2      = (_Float16*)alloc((size_t)N * DHID * 2);
    _Float16* H        = (_Float16*)alloc((size_t)N * DHID * 2);
    _Float16* W1t      = (_Float16*)alloc((size_t)DHID * DHID * 2);
    _Float16* W2t      = (_Float16*)alloc((size_t)DHID * DHID * 2);

    (void)hipMemsetAsync(bcur, 0, (size_t)nbuck * 4, stream);

    // K0: edge partition ∥ W1/W2 fp16 transposes
    k_part<<<nPart + 2, 256, 0, stream>>>(ei, E, nbuck, bcur, packed, W1, W2, W1t, W2t, nPart);
    // K1: p2b (first 196 blocks) ∥ gemm1 (rest) — independent work, p2b hidden
    k_mid<<<nbuck + nRB, 256, 0, stream>>>(packed, bcur, row_ptr, dinv, csr, nbuck, N, E,
                                           x, W1t, Th);
    // K2: agg layer-1 -> H (pure gather, no barrier)
    k_agg_mid<<<(N + 15) / 16, 256, 0, stream>>>(Th, row_ptr, csr, dinv, b1, H, N);
    // K3: gemm2 -> Th2
    k_gemm_l2<<<nRB, 256, 0, stream>>>(H, W2t, Th2, N);
    // K4: final agg + Wl projection
    k_agg_fin<<<(N + 15) / 16, 256, 0, stream>>>(Th2, row_ptr, csr, dinv, b2, Wl, bl, out, N);
}